// Round 13
// baseline (444.956 us; speedup 1.0000x reference)
//
#include <hip/hip_runtime.h>
#include <hip/hip_bf16.h>

// ---------------------------------------------------------------------------
// Star-Transformer 2-layer forward — satellite branch only (relay chain is
// dead code for the output, established round 10).
// Round 24: FULL-K staging for the K=256 GEMMs. All prior pipeline levers
// (dbuf depth, counted vmcnt, smaller tiles, reg staging) were neutral or
// negative; the untried direction is BIGGER stages: K=256 fits entirely in
// LDS (128x128 tile, 2 x 64KB = 128KB, legal on gfx950). One stage of 32
// async global_load_lds per thread (MLP-hidden, single latency exposure),
// ONE barrier, then 128 uninterrupted MFMAs — the per-K-step vmcnt(0)
// drain that bounded rounds 12-21 is eliminated structurally. 1 block/CU,
// but the single transfer phase is BW-bound (A re-reads are L3-resident),
// not latency-bound like f2's old 16-round-trip pathology.
// f2 (K=1024, doesn't fit) keeps the r19-proven 64x64 BK=64 kernel.
// Round 23 retained: k_ln_relay merge; dual-launch (hoisted-KV + layer-0
// qkv); cvt+bias single launch. Round 13 retained: BN1 stats fused into
// attn; BN2 stats + BN1-residual apply fused into f2 epilogue; BN2+leaky
// fused into final transpose; bf16 C-repack through LDS; hoisted
// [embs;relay0] K/V projections; BN2+LN fused at layer boundary.
// Row-major activations (row, channel), C=256 contiguous.
// ---------------------------------------------------------------------------

using bf16 = __hip_bfloat16;
typedef __attribute__((ext_vector_type(8))) short bf16x8v;
typedef __attribute__((ext_vector_type(4))) float f32x4;

namespace {
constexpr int kBT = 1024;
constexpr int kC = 256;
constexpr int kV = 17;
constexpr int kT = 256;
constexpr int kDIN = 1024;
constexpr int kRows = kBT * kV;                  // 17408
constexpr int kRowsE = kRows + kBT;              // 18432 = embs + relay0
constexpr float kInvSqrtDk = 0.17677669529663687f;
constexpr size_t SZ_BIG = (size_t)kRows * kC;
}  // namespace

__constant__ int c_nbi[17][5] = {
    {0, 1, 2, 5, 6},   {0, 1, 3, 0, 0},   {0, 2, 4, 0, 0},  {1, 3, 0, 0, 0},
    {2, 4, 0, 0, 0},   {0, 5, 7, 11, 0},  {0, 6, 8, 12, 0}, {5, 7, 9, 0, 0},
    {6, 8, 12, 0, 0},  {7, 9, 0, 0, 0},   {8, 10, 0, 0, 0}, {8, 11, 13, 0, 0},
    {10, 12, 14, 0, 0},{11, 13, 15, 0, 0},{12, 14, 16, 0, 0},
    {13, 15, 0, 0, 0}, {14, 16, 0, 0, 0}};
__constant__ int c_ncnt[17] = {5, 3, 3, 2, 2, 4, 4, 3, 3, 2, 2, 3, 3, 3, 3, 2, 2};

__device__ inline float bf2f(unsigned short s) {
  unsigned int u = ((unsigned int)s) << 16;
  float f;
  __builtin_memcpy(&f, &u, 4);
  return f;
}
__device__ inline unsigned short f2bf(float f) {
  unsigned int u;
  __builtin_memcpy(&u, &f, 4);
  unsigned int r = (u + 0x7fffu + ((u >> 16) & 1u)) >> 16;  // RNE
  return (unsigned short)r;
}
__device__ inline float4 ldbf4(const bf16* p) {
  ushort4 u = *(const ushort4*)p;
  return make_float4(bf2f(u.x), bf2f(u.y), bf2f(u.z), bf2f(u.w));
}
__device__ inline void stbf4(bf16* p, float4 v) {
  ushort4 u = make_ushort4(f2bf(v.x), f2bf(v.y), f2bf(v.z), f2bf(v.w));
  *(ushort4*)p = u;
}
__device__ inline float dot4(float4 a, float4 b) {
  return a.x * b.x + a.y * b.y + a.z * b.z + a.w * b.w;
}

__device__ inline void async16(const bf16* g, bf16* l) {
  __builtin_amdgcn_global_load_lds(
      (const __attribute__((address_space(1))) void*)g,
      (__attribute__((address_space(3))) void*)l, 16, 0, 0);
}

// ---- full-K 128x128-tile GEMM body (K=256), bf16 out ----
// Entire K staged once into 128KB LDS (A 64KB + B 64KB); ONE barrier; then
// 128 MFMAs with zero intervening syncs. 1 block/CU.
__device__ __forceinline__ void gemm128_fullk_body(
    char* smem_raw, const bf16* __restrict__ A, const bf16* __restrict__ W,
    const float* __restrict__ bias, bf16* __restrict__ outB, int N, int flags,
    int row0, int col0) {
  constexpr int KT = 256;
  bf16* As = (bf16*)smem_raw;               // 8 chunks x 4096 elems (64 KB)
  bf16* Bs = (bf16*)(smem_raw + 65536);     // 64 KB
  const int tid = threadIdx.x;
  const int wave = tid >> 6;
  const int lane = tid & 63;

  const int sub = lane >> 2;
  const int kq = (lane & 3) * 8;
  const int rg0 = (2 * wave + 0) * 16;
  const int rg1 = (2 * wave + 1) * 16;
  const bf16* ag0 = A + (size_t)(row0 + rg0 + sub) * KT + kq;
  const bf16* ag1 = A + (size_t)(row0 + rg1 + sub) * KT + kq;
  const bf16* bg0 = W + (size_t)(col0 + rg0 + sub) * KT + kq;
  const bf16* bg1 = W + (size_t)(col0 + rg1 + sub) * KT + kq;

  const int wm = wave >> 1, wn = wave & 1;
  const int fr = lane & 15;
  const int fk = (lane >> 4) * 8;

  // Stage ALL of K: 8 chunks x 4 loads = 32 async16/thread, one exposure.
#pragma unroll
  for (int kc = 0; kc < 8; ++kc) {
    const int off = kc * 32;
    async16(ag0 + off, As + kc * 4096 + rg0 * 32);
    async16(ag1 + off, As + kc * 4096 + rg1 * 32);
    async16(bg0 + off, Bs + kc * 4096 + rg0 * 32);
    async16(bg1 + off, Bs + kc * 4096 + rg1 * 32);
  }
  __syncthreads();  // single drain for the whole K extent

  f32x4 acc[4][4];
#pragma unroll
  for (int i = 0; i < 4; ++i)
#pragma unroll
    for (int j = 0; j < 4; ++j) acc[i][j] = (f32x4){0.f, 0.f, 0.f, 0.f};

#pragma unroll
  for (int kc = 0; kc < 8; ++kc) {
    bf16x8v af[4], bfv[4];
#pragma unroll
    for (int i = 0; i < 4; ++i)
      af[i] = *(const bf16x8v*)&As[kc * 4096 +
                                   (wm * 64 + i * 16 + fr) * 32 + fk];
#pragma unroll
    for (int j = 0; j < 4; ++j)
      bfv[j] = *(const bf16x8v*)&Bs[kc * 4096 +
                                    (wn * 64 + j * 16 + fr) * 32 + fk];
#pragma unroll
    for (int i = 0; i < 4; ++i)
#pragma unroll
      for (int j = 0; j < 4; ++j)
        acc[i][j] = __builtin_amdgcn_mfma_f32_16x16x32_bf16(af[i], bfv[j],
                                                            acc[i][j], 0, 0,
                                                            0);
  }
  __syncthreads();  // all reads done before C-repack overwrites As

  // bf16 out: stage C-tile in LDS (ushort 128x128 = 32 KB of the arena),
  // then 8 passes of 16 rows x 256B fully-coalesced stores.
  unsigned short* cs = (unsigned short*)smem_raw;
#pragma unroll
  for (int j = 0; j < 4; ++j) {
    int lc = wn * 64 + j * 16 + fr;
    float bv = bias ? bias[col0 + lc] : 0.f;
#pragma unroll
    for (int i = 0; i < 4; ++i) {
      int lr = wm * 64 + i * 16 + (lane >> 4) * 4;
#pragma unroll
      for (int r = 0; r < 4; ++r) {
        float v = acc[i][j][r] + bv;
        if (flags & 1) v = fmaxf(v, 0.f);
        cs[(lr + r) * 128 + lc] = f2bf(v);
      }
    }
  }
  __syncthreads();
#pragma unroll
  for (int p = 0; p < 8; ++p) {
    int lr = p * 16 + (tid >> 4);
    int lc = (tid & 15) * 8;
    *(bf16x8v*)&outB[(size_t)(row0 + lr) * N + col0 + lc] =
        *(const bf16x8v*)&cs[lr * 128 + lc];
  }
}

// ---- single GEMM launch (K=256, full-K staging) ----
__global__ __launch_bounds__(256, 1) void k_mfma_gemm(
    const bf16* __restrict__ A, const bf16* __restrict__ W,
    const float* __restrict__ bias, bf16* __restrict__ outB, int N,
    int flags) {
  __shared__ __align__(16) char smem_raw[131072];
  gemm128_fullk_body(smem_raw, A, W, bias, outB, N, flags, blockIdx.x * 128,
                     blockIdx.y * 128);
}

// ---- dual GEMM launch: two independent K=256 bf16-out GEMMs in one grid.
__global__ __launch_bounds__(256, 1) void k_mfma_gemm_dual(
    const bf16* __restrict__ A0, const bf16* __restrict__ W0,
    const float* __restrict__ b0, bf16* __restrict__ o0, int N0, int gx0,
    int nb0, const bf16* __restrict__ A1, const bf16* __restrict__ W1,
    const float* __restrict__ b1, bf16* __restrict__ o1, int N1, int gx1) {
  __shared__ __align__(16) char smem_raw[131072];
  const int bid = blockIdx.x;
  if (bid < nb0) {
    int bx = bid % gx0, by = bid / gx0;
    gemm128_fullk_body(smem_raw, A0, W0, b0, o0, N0, 4, bx * 128, by * 128);
  } else {
    int local = bid - nb0;
    int bx = local % gx1, by = local / gx1;
    gemm128_fullk_body(smem_raw, A1, W1, b1, o1, N1, 4, bx * 128, by * 128);
  }
}

// ---- f2-dedicated 64x64-tile GEMM (r19, proven): KT=1024, fp32 out,
// BN1-residual apply + BN2 partial stats. 1088 blocks -> ~4 blocks/CU.
__global__ __launch_bounds__(256, 4) void k_mfma_gemm64(
    const bf16* __restrict__ A, const bf16* __restrict__ W,
    const float* __restrict__ bias, const float* __restrict__ res,
    float* __restrict__ outF, const float* __restrict__ bnScI,
    const float* __restrict__ bnShI, float* __restrict__ partOut, int nbPart,
    int N) {
  constexpr int KT = 1024;
  __shared__ __align__(16) bf16 As[2][4096];  // 2 x (2 chunks x 64 x 32)
  __shared__ __align__(16) bf16 Bs[2][4096];
  __shared__ float sred[4 * 64];
  __shared__ float qred[4 * 64];
  const int tid = threadIdx.x;
  const int wave = tid >> 6;
  const int lane = tid & 63;
  const int row0 = blockIdx.x * 64;
  const int col0 = blockIdx.y * 64;

  const int srow = wave * 16 + (lane >> 2);
  const int skq = (lane & 3) * 8;
  const bf16* ag = A + (size_t)(row0 + srow) * KT + skq;
  const bf16* bg = W + (size_t)(col0 + srow) * KT + skq;

  const int wm = wave >> 1, wn = wave & 1;
  const int fr = lane & 15;
  const int fk = (lane >> 4) * 8;

  f32x4 acc[2][2];
#pragma unroll
  for (int i = 0; i < 2; ++i)
#pragma unroll
    for (int j = 0; j < 2; ++j) acc[i][j] = (f32x4){0.f, 0.f, 0.f, 0.f};

#define STAGE64x64(buf, koff)                                      \
  do {                                                             \
    _Pragma("unroll") for (int kc = 0; kc < 2; ++kc) {             \
      async16(ag + (koff) + kc * 32,                               \
              &As[(buf)][kc * 2048 + wave * 512]);                 \
      async16(bg + (koff) + kc * 32,                               \
              &Bs[(buf)][kc * 2048 + wave * 512]);                 \
    }                                                              \
  } while (0)

  STAGE64x64(0, 0);
  __syncthreads();

  for (int k0 = 0; k0 < KT; k0 += 64) {
    const int cur = (k0 >> 6) & 1;
    if (k0 + 64 < KT) STAGE64x64(cur ^ 1, k0 + 64);
#pragma unroll
    for (int kc = 0; kc < 2; ++kc) {
      bf16x8v af[2], bfv[2];
#pragma unroll
      for (int i = 0; i < 2; ++i)
        af[i] = *(const bf16x8v*)&As[cur][kc * 2048 +
                                          (wm * 32 + i * 16 + fr) * 32 + fk];
#pragma unroll
      for (int j = 0; j < 2; ++j)
        bfv[j] = *(const bf16x8v*)&Bs[cur][kc * 2048 +
                                           (wn * 32 + j * 16 + fr) * 32 + fk];
#pragma unroll
      for (int i = 0; i < 2; ++i)
#pragma unroll
        for (int j = 0; j < 2; ++j)
          acc[i][j] = __builtin_amdgcn_mfma_f32_16x16x32_bf16(af[i], bfv[j],
                                                              acc[i][j], 0, 0,
                                                              0);
    }
    __syncthreads();
  }
#undef STAGE64x64

  // fp32 epilogue: out = acc + bias + res*bnSc + bnSh; BN2 partial stats.
  const int crow = row0 + wm * 32;
  const int ccol = col0 + wn * 32;
  float colS[2] = {0.f, 0.f};
  float colQ[2] = {0.f, 0.f};
#pragma unroll
  for (int j = 0; j < 2; ++j) {
    int col = ccol + j * 16 + fr;
    float bv = bias[col];
    float rsc = bnScI[col], rsh = bnShI[col];
#pragma unroll
    for (int i = 0; i < 2; ++i) {
      int rowb = crow + i * 16 + (lane >> 4) * 4;
#pragma unroll
      for (int r = 0; r < 4; ++r) {
        size_t row = (size_t)(rowb + r);
        float v = acc[i][j][r] + bv + res[row * N + col] * rsc + rsh;
        outF[row * N + col] = v;
        colS[j] += v;
        colQ[j] += v * v;
      }
    }
  }
#pragma unroll
  for (int j = 0; j < 2; ++j) {
    colS[j] += __shfl_xor(colS[j], 16);
    colS[j] += __shfl_xor(colS[j], 32);
    colQ[j] += __shfl_xor(colQ[j], 16);
    colQ[j] += __shfl_xor(colQ[j], 32);
  }
  if (lane < 16) {
#pragma unroll
    for (int j = 0; j < 2; ++j) {
      sred[wave * 64 + j * 16 + fr] = colS[j];
      qred[wave * 64 + j * 16 + fr] = colQ[j];
    }
  }
  __syncthreads();
  if (tid < 64) {
    int c = tid;
    int wsel = c >> 5, off = c & 31;
    float s = sred[wsel * 64 + off] + sred[(wsel + 2) * 64 + off];
    float q = qred[wsel * 64 + off] + qred[(wsel + 2) * 64 + off];
    int col = col0 + c;
    partOut[(size_t)blockIdx.x * kC + col] = s;
    partOut[(size_t)(nbPart + blockIdx.x) * kC + col] = q;
  }
}

// data (B,C,V,T) -> nodes fp32 rows + embs bf16 rows
__global__ __launch_bounds__(256) void k_xform_in(const float* __restrict__ data,
                                                  float* __restrict__ nodes,
                                                  bf16* __restrict__ embs_bf) {
  __shared__ float tile[32][33];
  int ct = blockIdx.x * 32, tt = blockIdx.y * 32;
  int bv = blockIdx.z;
  int b = bv / kV, v = bv - b * kV;
  int tx = threadIdx.x & 31, ty = threadIdx.x >> 5;
  for (int i = ty; i < 32; i += 8)
    tile[i][tx] = data[(((size_t)b * kC + ct + i) * kV + v) * kT + tt + tx];
  __syncthreads();
  for (int i = ty; i < 32; i += 8) {
    size_t s = (size_t)b * kT + tt + i;
    size_t idx = (s * kV + v) * kC + ct + tx;
    float val = tile[tx][i];
    nodes[idx] = val;
    embs_bf[idx] = __float2bfloat16(val);
  }
}

// final transpose fused with BN2-apply + leaky
__global__ __launch_bounds__(256) void k_xform_out(const float* __restrict__ Z,
                                                   const float* __restrict__ scale,
                                                   const float* __restrict__ shift,
                                                   float* __restrict__ out) {
  __shared__ float tile[32][33];
  int ct = blockIdx.x * 32, tt = blockIdx.y * 32;
  int bv = blockIdx.z;
  int b = bv / kV, v = bv - b * kV;
  int tx = threadIdx.x & 31, ty = threadIdx.x >> 5;
  float sc = scale[ct + tx], sh = shift[ct + tx];
  for (int i = ty; i < 32; i += 8) {
    size_t s = (size_t)b * kT + tt + i;
    float val = Z[(s * kV + v) * kC + ct + tx] * sc + sh;
    val = (val > 0.f) ? val : 0.01f * val;
    tile[i][tx] = val;
  }
  __syncthreads();
  for (int i = ty; i < 32; i += 8)
    out[(((size_t)b * kC + ct + i) * kV + v) * kT + tt + tx] = tile[tx][i];
}

// merged: layer-0 LN (blocks [0, kRows/4)) + relay0 init (rest).
__global__ __launch_bounds__(256) void k_ln_relay(
    const float* __restrict__ nodes, const float* __restrict__ g,
    const float* __restrict__ b, float* __restrict__ O,
    bf16* __restrict__ Ob, bf16* __restrict__ relay0_bf) {
  int t = threadIdx.x;
  int bid = blockIdx.x;
  if (bid < kRows / 4) {
    int row = bid * 4 + (t >> 6);
    int c4 = (t & 63) * 4;
    size_t i = (size_t)row * kC + c4;
    float4 x = *(const float4*)(nodes + i);
    float s = x.x + x.y + x.z + x.w;
    float q = dot4(x, x);
#pragma unroll
    for (int o = 32; o >= 1; o >>= 1) {
      s += __shfl_xor(s, o);
      q += __shfl_xor(q, o);
    }
    float m = s * (1.f / 256.f);
    float var = q * (1.f / 256.f) - m * m;
    float rs = rsqrtf(var + 1e-6f);
    float4 g4 = *(const float4*)(g + c4);
    float4 b4 = *(const float4*)(b + c4);
    float4 o4 = make_float4((x.x - m) * rs * g4.x + b4.x,
                            (x.y - m) * rs * g4.y + b4.y,
                            (x.z - m) * rs * g4.z + b4.z,
                            (x.w - m) * rs * g4.w + b4.w);
    *(float4*)(O + i) = o4;
    stbf4(Ob + i, o4);
  } else {
    int s = (bid - kRows / 4) * 4 + (t >> 6);
    int c4 = (t & 63) * 4;
    float4 acc = make_float4(0.f, 0.f, 0.f, 0.f);
#pragma unroll
    for (int v = 0; v < kV; ++v) {
      float4 x = *(const float4*)(nodes + ((size_t)s * kV + v) * kC + c4);
      acc.x += x.x; acc.y += x.y; acc.z += x.z; acc.w += x.w;
    }
    float4 r =
        make_float4(acc.x / 17.f, acc.y / 17.f, acc.z / 17.f, acc.w / 17.f);
    stbf4(relay0_bf + (size_t)s * kC + c4, r);
  }
}

// satellite attention + fused BN1 partial stats (see round 13).
__global__ __launch_bounds__(256) void k_attn_sat(const bf16* __restrict__ qkv,
                                                  const bf16* __restrict__ akav,
                                                  float* __restrict__ z,
                                                  float* __restrict__ part,
                                                  int nb) {
  __shared__ float sS[4][256];
  __shared__ float qS[4][256];
  int t = threadIdx.x;
  int w = t >> 6;
  int rl = blockIdx.x * 4 + w;
  int lane = t & 63;
  int s = rl / kV, l = rl - s * kV;
  int c4 = lane * 4;
  float4 q = ldbf4(qkv + (size_t)rl * 768 + c4);
  int cnt = c_ncnt[l];
  float sc[7];
  int nrow[5];
#pragma unroll
  for (int wd = 0; wd < 5; ++wd) {
    nrow[wd] = s * kV + c_nbi[l][wd];
    float4 k = ldbf4(qkv + (size_t)nrow[wd] * 768 + 256 + c4);
    float p = dot4(q, k);
    p += __shfl_xor(p, 1, 8);
    p += __shfl_xor(p, 2, 8);
    p += __shfl_xor(p, 4, 8);
    sc[wd] = (wd < cnt) ? p * kInvSqrtDk : -1e30f;
  }
  {
    float4 k = ldbf4(akav + (size_t)rl * 1024 + c4);
    float p = dot4(q, k);
    p += __shfl_xor(p, 1, 8);
    p += __shfl_xor(p, 2, 8);
    p += __shfl_xor(p, 4, 8);
    sc[5] = p * kInvSqrtDk;
  }
  {
    float4 k = ldbf4(akav + (size_t)(kRows + s) * 1024 + c4);
    float p = dot4(q, k);
    p += __shfl_xor(p, 1, 8);
    p += __shfl_xor(p, 2, 8);
    p += __shfl_xor(p, 4, 8);
    sc[6] = p * kInvSqrtDk;
  }
  float mx = sc[0];
#pragma unroll
  for (int wd = 1; wd < 7; ++wd) mx = fmaxf(mx, sc[wd]);
  float den = 0.f;
#pragma unroll
  for (int wd = 0; wd < 7; ++wd) {
    sc[wd] = __expf(sc[wd] - mx);
    den += sc[wd];
  }
  float inv = 1.f / den;
  float4 acc = make_float4(0.f, 0.f, 0.f, 0.f);
#pragma unroll
  for (int wd = 0; wd < 5; ++wd) {
    float4 v = ldbf4(qkv + (size_t)nrow[wd] * 768 + 512 + c4);
    acc.x += sc[wd] * v.x; acc.y += sc[wd] * v.y;
    acc.z += sc[wd] * v.z; acc.w += sc[wd] * v.w;
  }
  {
    float4 v = ldbf4(akav + (size_t)rl * 1024 + 256 + c4);
    acc.x += sc[5] * v.x; acc.y += sc[5] * v.y;
    acc.z += sc[5] * v.z; acc.w += sc[5] * v.w;
  }
  {
    float4 v = ldbf4(akav + (size_t)(kRows + s) * 1024 + 256 + c4);
    acc.x += sc[6] * v.x; acc.y += sc[6] * v.y;
    acc.z += sc[6] * v.z; acc.w += sc[6] * v.w;
  }
  size_t zi = (size_t)rl * kC + c4;
  float4 xv = *(const float4*)(z + zi);
  float4 o = make_float4(xv.x + acc.x * inv, xv.y + acc.y * inv,
                         xv.z + acc.z * inv, xv.w + acc.w * inv);
  *(float4*)(z + zi) = o;
  sS[w][c4 + 0] = o.x; sS[w][c4 + 1] = o.y;
  sS[w][c4 + 2] = o.z; sS[w][c4 + 3] = o.w;
  qS[w][c4 + 0] = o.x * o.x; qS[w][c4 + 1] = o.y * o.y;
  qS[w][c4 + 2] = o.z * o.z; qS[w][c4 + 3] = o.w * o.w;
  __syncthreads();
  float ps = sS[0][t] + sS[1][t] + sS[2][t] + sS[3][t];
  float pq = qS[0][t] + qS[1][t] + qS[2][t] + qS[3][t];
  part[(size_t)blockIdx.x * kC + t] = ps;
  part[(size_t)(nb + blockIdx.x) * kC + t] = pq;
}

// BN stage 2: block per channel
__global__ __launch_bounds__(256) void k_bn_finalize(const float* __restrict__ part,
                                                     int nb, float inv_n,
                                                     const float* __restrict__ g,
                                                     const float* __restrict__ b,
                                                     float* __restrict__ scale,
                                                     float* __restrict__ shift) {
  int c = blockIdx.x;
  int t = threadIdx.x;
  float s = 0.f, q = 0.f;
  for (int i = t; i < nb; i += 256) {
    s += part[(size_t)i * kC + c];
    q += part[(size_t)(nb + i) * kC + c];
  }
#pragma unroll
  for (int o = 32; o >= 1; o >>= 1) {
    s += __shfl_xor(s, o);
    q += __shfl_xor(q, o);
  }
  __shared__ float ws[4], wq[4];
  int wid = t >> 6;
  if ((t & 63) == 0) { ws[wid] = s; wq[wid] = q; }
  __syncthreads();
  if (t == 0) {
    float S = ws[0] + ws[1] + ws[2] + ws[3];
    float Q = wq[0] + wq[1] + wq[2] + wq[3];
    float m = S * inv_n;
    float var = Q * inv_n - m * m;
    float sc = g[c] * rsqrtf(var + 1e-5f);
    scale[c] = sc;
    shift[c] = b[c] - m * sc;
  }
}

// BN stage 3: 4 rows/block, float4; writes fp32 and/or bf16
__global__ __launch_bounds__(256) void k_bn_apply(const float* __restrict__ Z,
                                                  const float* __restrict__ scale,
                                                  const float* __restrict__ shift,
                                                  float* __restrict__ outF,
                                                  bf16* __restrict__ outB,
                                                  int leaky) {
  int t = threadIdx.x;
  int row = blockIdx.x * 4 + (t >> 6);
  int c4 = (t & 63) * 4;
  size_t i = (size_t)row * kC + c4;
  float4 z = *(const float4*)(Z + i);
  float4 sc = *(const float4*)(scale + c4);
  float4 sh = *(const float4*)(shift + c4);
  float4 v = make_float4(z.x * sc.x + sh.x, z.y * sc.y + sh.y,
                         z.z * sc.z + sh.z, z.w * sc.w + sh.w);
  if (leaky) {
    v.x = (v.x > 0.f) ? v.x : 0.01f * v.x;
    v.y = (v.y > 0.f) ? v.y : 0.01f * v.y;
    v.z = (v.z > 0.f) ? v.z : 0.01f * v.z;
    v.w = (v.w > 0.f) ? v.w : 0.01f * v.w;
  }
  if (outF) *(float4*)(outF + i) = v;
  if (outB) stbf4(outB + i, v);
}

// Fused BN2(leaky)+LN at the layer boundary
__global__ __launch_bounds__(256) void k_bn_ln(
    const float* __restrict__ Z, const float* __restrict__ scale,
    const float* __restrict__ shift, const float* __restrict__ g,
    const float* __restrict__ b, float* __restrict__ xnOut,
    bf16* __restrict__ actOut) {
  int t = threadIdx.x;
  int row = blockIdx.x * 4 + (t >> 6);
  int c4 = (t & 63) * 4;
  size_t i = (size_t)row * kC + c4;
  float4 z = *(const float4*)(Z + i);
  float4 sc = *(const float4*)(scale + c4);
  float4 sh = *(const float4*)(shift + c4);
  float4 v = make_float4(z.x * sc.x + sh.x, z.y * sc.y + sh.y,
                         z.z * sc.z + sh.z, z.w * sc.w + sh.w);
  v.x = (v.x > 0.f) ? v.x : 0.01f * v.x;
  v.y = (v.y > 0.f) ? v.y : 0.01f * v.y;
  v.z = (v.z > 0.f) ? v.z : 0.01f * v.z;
  v.w = (v.w > 0.f) ? v.w : 0.01f * v.w;
  float s = v.x + v.y + v.z + v.w;
  float q = dot4(v, v);
#pragma unroll
  for (int o = 32; o >= 1; o >>= 1) {
    s += __shfl_xor(s, o);
    q += __shfl_xor(q, o);
  }
  float m = s * (1.f / 256.f);
  float var = q * (1.f / 256.f) - m * m;
  float rs = rsqrtf(var + 1e-6f);
  float4 g4 = *(const float4*)(g + c4);
  float4 b4 = *(const float4*)(b + c4);
  float4 o4 = make_float4((v.x - m) * rs * g4.x + b4.x,
                          (v.y - m) * rs * g4.y + b4.y,
                          (v.z - m) * rs * g4.z + b4.z,
                          (v.w - m) * rs * g4.w + b4.w);
  *(float4*)(xnOut + i) = o4;
  stbf4(actOut + i, o4);
}

// batched f32->bf16 conversion (12 chunks) + bias copies (10 x 256), one
// launch: blockIdx.y < 12 -> cvt; blockIdx.y == 12 -> bias copy.
struct CvtTab {
  const float* src[12];
  bf16* dst[12];
  int n[12];
  const float* bsrc[10];
  float* bdst[10];
};
__global__ __launch_bounds__(256) void k_cvt_multi(CvtTab t) {
  int c = blockIdx.y;
  if (c == 12) {
    if (blockIdx.x < 10) t.bdst[blockIdx.x][threadIdx.x] = t.bsrc[blockIdx.x][threadIdx.x];
    return;
  }
  int i = (blockIdx.x * 256 + threadIdx.x) * 4;
  if (i >= t.n[c]) return;
  float4 v = *(const float4*)(t.src[c] + i);
  stbf4(t.dst[c] + i, v);
}

extern "C" void kernel_launch(void* const* d_in, const int* in_sizes, int n_in,
                              void* d_out, int out_size, void* d_ws, size_t ws_size,
                              hipStream_t stream) {
  const float* data = (const float*)d_in[0];
  const float* ln_g = (const float*)d_in[1];
  const float* ln_b = (const float*)d_in[2];
  const float* jq_w = (const float*)d_in[3];
  const float* jq_b = (const float*)d_in[4];
  const float* jk_w = (const float*)d_in[5];
  const float* jk_b = (const float*)d_in[6];
  const float* jv_w = (const float*)d_in[7];
  const float* jv_b = (const float*)d_in[8];
  const float* jbn_g = (const float*)d_in[9];
  const float* jbn_b = (const float*)d_in[10];
  const float* jf1_w = (const float*)d_in[11];
  const float* jf1_b = (const float*)d_in[12];
  const float* jf2_w = (const float*)d_in[13];
  const float* jf2_b = (const float*)d_in[14];
  const float* jfbn_g = (const float*)d_in[15];
  const float* jfbn_b = (const float*)d_in[16];
  // d_in[17..30]: relay-branch weights — dead code, unused.
  float* out = (float*)d_out;

  // ---- arena ----
  float* f = (float*)d_ws;
  float* nodes = f;    f += SZ_BIG;
  float* xn = f;       f += SZ_BIG;           // LN out -> z -> y2
  float* part = f;     f += 2 * (kRows / 4) * kC;  // BN partials (nb<=4352)
  float* scale = f;    f += kC;
  float* shift = f;    f += kC;
  float* cb_jqkv = f;  f += 2 * 768;
  float* cb_kv4 = f;   f += 1024;

  bf16* bfa = (bf16*)f;
  bf16* act_bf = bfa;   bfa += SZ_BIG;                 // 17408 x 256
  bf16* embsX_bf = bfa; bfa += (size_t)kRowsE * kC;    // [embs; relay0]
  bf16* P = bfa;        bfa += (size_t)kRows * kDIN;   // qkv (768) / h (1024)
  bf16* akavBuf = bfa;  bfa += (size_t)kRowsE * 1024;  // [k0|v0|k1|v1]
  bf16* Wjqkv = bfa;    bfa += 2 * 768 * 256;
  bf16* Wkv4 = bfa;     bfa += 1024 * 256;
  bf16* Wjf1 = bfa;     bfa += 2 * 1024 * 256;
  bf16* Wjf2 = bfa;     bfa += 2 * 256 * 1024;

  bf16* relay0_bf = embsX_bf + SZ_BIG;  // rows kRows..kRowsE-1
  bf16* qkv_bf = P;                     // 17408 x 768
  bf16* h_bf = P;                       // 17408 x 1024
  float* y2 = xn;

  auto gemm = [&](const bf16* A, const bf16* W, const float* bias,
                  bf16* oB, int M, int N, int flags) {
    dim3 g(M / 128, N / 128);
    k_mfma_gemm<<<g, 256, 0, stream>>>(A, W, bias, oB, N, flags);
  };

  // ---- weight conversion + bias copies (one launch) ----
  {
    CvtTab t;
    for (int i = 0; i < 2; ++i) {
      const size_t om = (size_t)i * kC * kC;
      const float* s3[3] = {jq_w + om, jk_w + om, jv_w + om};
      bf16* d3[3] = {Wjqkv + (size_t)i * 768 * 256,
                     Wjqkv + (size_t)i * 768 * 256 + 65536,
                     Wjqkv + (size_t)i * 768 * 256 + 131072};
      for (int j = 0; j < 3; ++j) {
        t.src[i * 3 + j] = s3[j];
        t.dst[i * 3 + j] = d3[j];
        t.n[i * 3 + j] = 65536;
      }
    }
    // Wkv4 = [k0 | v0 | k1 | v1]
    t.src[6] = jk_w;                 t.dst[6] = Wkv4;               t.n[6] = 65536;
    t.src[7] = jv_w;                 t.dst[7] = Wkv4 + 65536;       t.n[7] = 65536;
    t.src[8] = jk_w + (size_t)65536; t.dst[8] = Wkv4 + 131072;      t.n[8] = 65536;
    t.src[9] = jv_w + (size_t)65536; t.dst[9] = Wkv4 + 196608;      t.n[9] = 65536;
    t.src[10] = jf1_w; t.dst[10] = Wjf1; t.n[10] = 2 * 1024 * 256;
    t.src[11] = jf2_w; t.dst[11] = Wjf2; t.n[11] = 2 * 256 * 1024;
    for (int i = 0; i < 2; ++i) {
      t.bsrc[i * 3 + 0] = jq_b + (size_t)i * kC;
      t.bsrc[i * 3 + 1] = jk_b + (size_t)i * kC;
      t.bsrc[i * 3 + 2] = jv_b + (size_t)i * kC;
      t.bdst[i * 3 + 0] = cb_jqkv + i * 768;
      t.bdst[i * 3 + 1] = cb_jqkv + i * 768 + 256;
      t.bdst[i * 3 + 2] = cb_jqkv + i * 768 + 512;
    }
    t.bsrc[6] = jk_b;       t.bdst[6] = cb_kv4;
    t.bsrc[7] = jv_b;       t.bdst[7] = cb_kv4 + 256;
    t.bsrc[8] = jk_b + kC;  t.bdst[8] = cb_kv4 + 512;
    t.bsrc[9] = jv_b + kC;  t.bdst[9] = cb_kv4 + 768;
    k_cvt_multi<<<dim3(512, 13), 256, 0, stream>>>(t);
  }

  k_xform_in<<<dim3(8, 8, 4 * kV), 256, 0, stream>>>(data, nodes, embsX_bf);

  // merged layer-0 LN + relay0 init (both consume nodes)
  k_ln_relay<<<kRows / 4 + kBT / 4, 256, 0, stream>>>(nodes, ln_g, ln_b, xn,
                                                      act_bf, relay0_bf);

  // dual launch: hoisted KV projections (both layers) + layer-0 qkv.
  {
    const int gx0 = kRowsE / 128, nb0 = gx0 * (1024 / 128);  // 144*8=1152
    const int gx1 = kRows / 128, nb1 = gx1 * (768 / 128);    // 136*6=816
    k_mfma_gemm_dual<<<nb0 + nb1, 256, 0, stream>>>(
        embsX_bf, Wkv4, cb_kv4, akavBuf, 1024, gx0, nb0,
        act_bf, Wjqkv, cb_jqkv, qkv_bf, 768, gx1);
  }

  for (int i = 0; i < 2; ++i) {
    const size_t ob = (size_t)i * kC, ofb1 = (size_t)i * kDIN;
    const bf16* Wf1 = Wjf1 + (size_t)i * 1024 * 256;
    const bf16* Wf2 = Wjf2 + (size_t)i * 256 * 1024;
    const int nbA = kRows / 4;    // attn-fused BN1 partials
    const int nbG = kRows / 64;   // f2-64-fused BN2 partials (272)

    if (i == 1) {
      // layer-1 qkv (layer-0 qkv was in the dual launch)
      gemm(act_bf, Wjqkv + (size_t)768 * 256, cb_jqkv + 768, qkv_bf, kRows,
           768, 4);
    }
    // z = xn + att; fused BN1 partial stats
    k_attn_sat<<<kRows / 4, 256, 0, stream>>>(qkv_bf, akavBuf + (size_t)i * 512,
                                              xn, part, nbA);
    k_bn_finalize<<<kC, 256, 0, stream>>>(part, nbA, 1.f / kRows, jbn_g + ob,
                                          jbn_b + ob, scale, shift);
    // BN1 apply -> act_bf only (fp32 residual applied on the fly in f2)
    k_bn_apply<<<kRows / 4, 256, 0, stream>>>(xn, scale, shift, nullptr,
                                              act_bf, 0);
    gemm(act_bf, Wf1, jf1_b + ofb1, h_bf, kRows, 1024, 4 | 1);
    // f2 (64x64 tiles): y2 = h@Wf2 + b + (xn*scale+shift); BN2 partials.
    k_mfma_gemm64<<<dim3(kRows / 64, kC / 64), 256, 0, stream>>>(
        h_bf, Wf2, jf2_b + ob, xn, y2, scale, shift, part, nbG, kC);
    k_bn_finalize<<<kC, 256, 0, stream>>>(part, nbG, 1.f / kRows, jfbn_g + ob,
                                          jfbn_b + ob, scale, shift);
    if (i == 0) {
      // fused BN2(leaky) + layer-1 LN (reads y2, writes xn + act_bf)
      k_bn_ln<<<kRows / 4, 256, 0, stream>>>(y2, scale, shift, ln_g + kC,
                                             ln_b + kC, xn, act_bf);
    }
    // i == 1: BN2 apply + leaky fused into k_xform_out below.
  }

  k_xform_out<<<dim3(8, 8, 4 * kV), 256, 0, stream>>>(y2, scale, shift, out);
  (void)in_sizes; (void)n_in; (void)out_size; (void)ws_size;
}

// Round 14
// 395.804 us; speedup vs baseline: 1.1242x; 1.1242x over previous
//
#include <hip/hip_runtime.h>
#include <hip/hip_bf16.h>

// ---------------------------------------------------------------------------
// Star-Transformer 2-layer forward — satellite branch only (relay chain is
// dead code for the output, established round 10).
// Round 25: EXACT REVERT to round 23 (best measured: 400.6us). Round 24's
// full-K staging regressed (+44us): at 1 block/CU consecutive blocks on a
// CU serialize {stage->compute->epilogue} with no inter-block overlap.
// Design space for the K=256 GEMMs is closed: BK{32,64,128,fullK} x
// tile{64^2,128^2} x staging{LDS,reg} x sync{barrier,counted-vmcnt} all
// bracketed; r23's point (BK=32 dbuf 128^2 @4 blocks/CU) is the optimum.
// Round 23: k_ln_relay merge; dual-launch (hoisted-KV + layer-0 qkv).
// Round 19: f2 64x64 BK=64 kernel (grid-starvation fix, -26us).
// Round 13: BN1 stats fused into attn; BN2 stats + BN1-residual apply
// fused into f2 epilogue; BN2+leaky fused into final transpose; bf16
// C-repack through LDS; hoisted [embs;relay0] K/V projections; BN2+LN
// fused at layer boundary.
// Row-major activations (row, channel), C=256 contiguous.
// ---------------------------------------------------------------------------

using bf16 = __hip_bfloat16;
typedef __attribute__((ext_vector_type(8))) short bf16x8v;
typedef __attribute__((ext_vector_type(4))) float f32x4;

namespace {
constexpr int kBT = 1024;
constexpr int kC = 256;
constexpr int kV = 17;
constexpr int kT = 256;
constexpr int kDIN = 1024;
constexpr int kRows = kBT * kV;                  // 17408
constexpr int kRowsE = kRows + kBT;              // 18432 = embs + relay0
constexpr float kInvSqrtDk = 0.17677669529663687f;
constexpr size_t SZ_BIG = (size_t)kRows * kC;
}  // namespace

__constant__ int c_nbi[17][5] = {
    {0, 1, 2, 5, 6},   {0, 1, 3, 0, 0},   {0, 2, 4, 0, 0},  {1, 3, 0, 0, 0},
    {2, 4, 0, 0, 0},   {0, 5, 7, 11, 0},  {0, 6, 8, 12, 0}, {5, 7, 9, 0, 0},
    {6, 8, 12, 0, 0},  {7, 9, 0, 0, 0},   {8, 10, 0, 0, 0}, {8, 11, 13, 0, 0},
    {10, 12, 14, 0, 0},{11, 13, 15, 0, 0},{12, 14, 16, 0, 0},
    {13, 15, 0, 0, 0}, {14, 16, 0, 0, 0}};
__constant__ int c_ncnt[17] = {5, 3, 3, 2, 2, 4, 4, 3, 3, 2, 2, 3, 3, 3, 3, 2, 2};

__device__ inline float bf2f(unsigned short s) {
  unsigned int u = ((unsigned int)s) << 16;
  float f;
  __builtin_memcpy(&f, &u, 4);
  return f;
}
__device__ inline unsigned short f2bf(float f) {
  unsigned int u;
  __builtin_memcpy(&u, &f, 4);
  unsigned int r = (u + 0x7fffu + ((u >> 16) & 1u)) >> 16;  // RNE
  return (unsigned short)r;
}
__device__ inline float4 ldbf4(const bf16* p) {
  ushort4 u = *(const ushort4*)p;
  return make_float4(bf2f(u.x), bf2f(u.y), bf2f(u.z), bf2f(u.w));
}
__device__ inline void stbf4(bf16* p, float4 v) {
  ushort4 u = make_ushort4(f2bf(v.x), f2bf(v.y), f2bf(v.z), f2bf(v.w));
  *(ushort4*)p = u;
}
__device__ inline float dot4(float4 a, float4 b) {
  return a.x * b.x + a.y * b.y + a.z * b.z + a.w * b.w;
}

__device__ inline void async16(const bf16* g, bf16* l) {
  __builtin_amdgcn_global_load_lds(
      (const __attribute__((address_space(1))) void*)g,
      (__attribute__((address_space(3))) void*)l, 16, 0, 0);
}

// ---- shared 128x128-tile GEMM body (K=256), bf16-out path ----
// BK=32 double-buffered; 32 KB LDS arena -> 4 blocks/CU.
template <int KT>
__device__ __forceinline__ void gemm128_body(
    char* smem_raw, const bf16* __restrict__ A, const bf16* __restrict__ W,
    const float* __restrict__ bias, bf16* __restrict__ outB, int N, int flags,
    int row0, int col0) {
  bf16* As = (bf16*)smem_raw;              // 2 x 4096 elems (16 KB)
  bf16* Bs = (bf16*)(smem_raw + 16384);    // 2 x 4096 elems (16 KB)
  const int tid = threadIdx.x;
  const int wave = tid >> 6;
  const int lane = tid & 63;

  const int sub = lane >> 2;
  const int kq = (lane & 3) * 8;
  const int rg0 = (2 * wave + 0) * 16;
  const int rg1 = (2 * wave + 1) * 16;
  const bf16* ag0 = A + (size_t)(row0 + rg0 + sub) * KT + kq;
  const bf16* ag1 = A + (size_t)(row0 + rg1 + sub) * KT + kq;
  const bf16* bg0 = W + (size_t)(col0 + rg0 + sub) * KT + kq;
  const bf16* bg1 = W + (size_t)(col0 + rg1 + sub) * KT + kq;

  const int wm = wave >> 1, wn = wave & 1;
  const int fr = lane & 15;
  const int fk = (lane >> 4) * 8;

  f32x4 acc[4][4];
#pragma unroll
  for (int i = 0; i < 4; ++i)
#pragma unroll
    for (int j = 0; j < 4; ++j) acc[i][j] = (f32x4){0.f, 0.f, 0.f, 0.f};

#define STAGE32(buf, koff)                              \
  do {                                                  \
    async16(ag0 + (koff), As + (buf) * 4096 + rg0 * 32); \
    async16(ag1 + (koff), As + (buf) * 4096 + rg1 * 32); \
    async16(bg0 + (koff), Bs + (buf) * 4096 + rg0 * 32); \
    async16(bg1 + (koff), Bs + (buf) * 4096 + rg1 * 32); \
  } while (0)

  STAGE32(0, 0);
  __syncthreads();  // buf0 ready

  for (int k0 = 0; k0 < KT; k0 += 32) {
    const int cur = (k0 >> 5) & 1;
    if (k0 + 32 < KT) STAGE32(cur ^ 1, k0 + 32);  // in flight during MFMA
    bf16x8v af[4], bfv[4];
#pragma unroll
    for (int i = 0; i < 4; ++i)
      af[i] = *(const bf16x8v*)&As[cur * 4096 +
                                   (wm * 64 + i * 16 + fr) * 32 + fk];
#pragma unroll
    for (int j = 0; j < 4; ++j)
      bfv[j] = *(const bf16x8v*)&Bs[cur * 4096 +
                                    (wn * 64 + j * 16 + fr) * 32 + fk];
#pragma unroll
    for (int i = 0; i < 4; ++i)
#pragma unroll
      for (int j = 0; j < 4; ++j)
        acc[i][j] = __builtin_amdgcn_mfma_f32_16x16x32_bf16(af[i], bfv[j],
                                                            acc[i][j], 0, 0,
                                                            0);
    __syncthreads();
  }
#undef STAGE32

  // bf16 out: stage C-tile in LDS (ushort 128x128 = 32 KB arena), then
  // 8 passes of 16 rows x 256B fully-coalesced stores.
  unsigned short* cs = (unsigned short*)smem_raw;
#pragma unroll
  for (int j = 0; j < 4; ++j) {
    int lc = wn * 64 + j * 16 + fr;
    float bv = bias ? bias[col0 + lc] : 0.f;
#pragma unroll
    for (int i = 0; i < 4; ++i) {
      int lr = wm * 64 + i * 16 + (lane >> 4) * 4;
#pragma unroll
      for (int r = 0; r < 4; ++r) {
        float v = acc[i][j][r] + bv;
        if (flags & 1) v = fmaxf(v, 0.f);
        cs[(lr + r) * 128 + lc] = f2bf(v);
      }
    }
  }
  __syncthreads();
#pragma unroll
  for (int p = 0; p < 8; ++p) {
    int lr = p * 16 + (tid >> 4);
    int lc = (tid & 15) * 8;
    *(bf16x8v*)&outB[(size_t)(row0 + lr) * N + col0 + lc] =
        *(const bf16x8v*)&cs[lr * 128 + lc];
  }
}

// ---- single GEMM launch (K=256) ----
template <int KT>
__global__ __launch_bounds__(256, 4) void k_mfma_gemm(
    const bf16* __restrict__ A, const bf16* __restrict__ W,
    const float* __restrict__ bias, bf16* __restrict__ outB, int N,
    int flags) {
  __shared__ __align__(16) char smem_raw[32768];
  gemm128_body<KT>(smem_raw, A, W, bias, outB, N, flags, blockIdx.x * 128,
                   blockIdx.y * 128);
}

// ---- dual GEMM launch: two independent K=256 bf16-out GEMMs in one grid.
// Blocks [0, nb0) run GEMM0 (gx0 row-tiles fastest); rest run GEMM1.
__global__ __launch_bounds__(256, 4) void k_mfma_gemm_dual(
    const bf16* __restrict__ A0, const bf16* __restrict__ W0,
    const float* __restrict__ b0, bf16* __restrict__ o0, int N0, int gx0,
    int nb0, const bf16* __restrict__ A1, const bf16* __restrict__ W1,
    const float* __restrict__ b1, bf16* __restrict__ o1, int N1, int gx1) {
  __shared__ __align__(16) char smem_raw[32768];
  const int bid = blockIdx.x;
  if (bid < nb0) {
    int bx = bid % gx0, by = bid / gx0;
    gemm128_body<256>(smem_raw, A0, W0, b0, o0, N0, 4, bx * 128, by * 128);
  } else {
    int local = bid - nb0;
    int bx = local % gx1, by = local / gx1;
    gemm128_body<256>(smem_raw, A1, W1, b1, o1, N1, 4, bx * 128, by * 128);
  }
}

// ---- f2-dedicated 64x64-tile GEMM: KT=1024, fp32 out, BN1-residual apply
// + BN2 partial stats. Grid (M/64, N/64) = 1088 blocks -> ~4 blocks/CU.
__global__ __launch_bounds__(256, 4) void k_mfma_gemm64(
    const bf16* __restrict__ A, const bf16* __restrict__ W,
    const float* __restrict__ bias, const float* __restrict__ res,
    float* __restrict__ outF, const float* __restrict__ bnScI,
    const float* __restrict__ bnShI, float* __restrict__ partOut, int nbPart,
    int N) {
  constexpr int KT = 1024;
  __shared__ __align__(16) bf16 As[2][4096];  // 2 x (2 chunks x 64 x 32)
  __shared__ __align__(16) bf16 Bs[2][4096];
  __shared__ float sred[4 * 64];
  __shared__ float qred[4 * 64];
  const int tid = threadIdx.x;
  const int wave = tid >> 6;
  const int lane = tid & 63;
  const int row0 = blockIdx.x * 64;
  const int col0 = blockIdx.y * 64;

  // global src per-lane: row wave*16 + (lane>>2), cols (lane&3)*8..+7
  const int srow = wave * 16 + (lane >> 2);
  const int skq = (lane & 3) * 8;
  const bf16* ag = A + (size_t)(row0 + srow) * KT + skq;
  const bf16* bg = W + (size_t)(col0 + srow) * KT + skq;

  const int wm = wave >> 1, wn = wave & 1;
  const int fr = lane & 15;
  const int fk = (lane >> 4) * 8;

  f32x4 acc[2][2];
#pragma unroll
  for (int i = 0; i < 2; ++i)
#pragma unroll
    for (int j = 0; j < 2; ++j) acc[i][j] = (f32x4){0.f, 0.f, 0.f, 0.f};

  // LDS dest: wave-uniform base; HW scatters lane i at +16B*i.
#define STAGE64x64(buf, koff)                                      \
  do {                                                             \
    _Pragma("unroll") for (int kc = 0; kc < 2; ++kc) {             \
      async16(ag + (koff) + kc * 32,                               \
              &As[(buf)][kc * 2048 + wave * 512]);                 \
      async16(bg + (koff) + kc * 32,                               \
              &Bs[(buf)][kc * 2048 + wave * 512]);                 \
    }                                                              \
  } while (0)

  STAGE64x64(0, 0);
  __syncthreads();

  for (int k0 = 0; k0 < KT; k0 += 64) {
    const int cur = (k0 >> 6) & 1;
    if (k0 + 64 < KT) STAGE64x64(cur ^ 1, k0 + 64);
#pragma unroll
    for (int kc = 0; kc < 2; ++kc) {
      bf16x8v af[2], bfv[2];
#pragma unroll
      for (int i = 0; i < 2; ++i)
        af[i] = *(const bf16x8v*)&As[cur][kc * 2048 +
                                          (wm * 32 + i * 16 + fr) * 32 + fk];
#pragma unroll
      for (int j = 0; j < 2; ++j)
        bfv[j] = *(const bf16x8v*)&Bs[cur][kc * 2048 +
                                           (wn * 32 + j * 16 + fr) * 32 + fk];
#pragma unroll
      for (int i = 0; i < 2; ++i)
#pragma unroll
        for (int j = 0; j < 2; ++j)
          acc[i][j] = __builtin_amdgcn_mfma_f32_16x16x32_bf16(af[i], bfv[j],
                                                              acc[i][j], 0, 0,
                                                              0);
    }
    __syncthreads();
  }
#undef STAGE64x64

  // fp32 epilogue: out = acc + bias + res*bnSc + bnSh; BN2 partial stats.
  const int crow = row0 + wm * 32;
  const int ccol = col0 + wn * 32;
  float colS[2] = {0.f, 0.f};
  float colQ[2] = {0.f, 0.f};
#pragma unroll
  for (int j = 0; j < 2; ++j) {
    int col = ccol + j * 16 + fr;
    float bv = bias[col];
    float rsc = bnScI[col], rsh = bnShI[col];
#pragma unroll
    for (int i = 0; i < 2; ++i) {
      int rowb = crow + i * 16 + (lane >> 4) * 4;
#pragma unroll
      for (int r = 0; r < 4; ++r) {
        size_t row = (size_t)(rowb + r);
        float v = acc[i][j][r] + bv + res[row * N + col] * rsc + rsh;
        outF[row * N + col] = v;
        colS[j] += v;
        colQ[j] += v * v;
      }
    }
  }
  // reduce the 4 row-groups within the wave (lane bit4, bit5)
#pragma unroll
  for (int j = 0; j < 2; ++j) {
    colS[j] += __shfl_xor(colS[j], 16);
    colS[j] += __shfl_xor(colS[j], 32);
    colQ[j] += __shfl_xor(colQ[j], 16);
    colQ[j] += __shfl_xor(colQ[j], 32);
  }
  if (lane < 16) {
#pragma unroll
    for (int j = 0; j < 2; ++j) {
      sred[wave * 64 + j * 16 + fr] = colS[j];
      qred[wave * 64 + j * 16 + fr] = colQ[j];
    }
  }
  __syncthreads();
  if (tid < 64) {
    int c = tid;
    int wsel = c >> 5, off = c & 31;
    float s = sred[wsel * 64 + off] + sred[(wsel + 2) * 64 + off];
    float q = qred[wsel * 64 + off] + qred[(wsel + 2) * 64 + off];
    int col = col0 + c;
    partOut[(size_t)blockIdx.x * kC + col] = s;
    partOut[(size_t)(nbPart + blockIdx.x) * kC + col] = q;
  }
}

// data (B,C,V,T) -> nodes fp32 rows + embs bf16 rows
__global__ __launch_bounds__(256) void k_xform_in(const float* __restrict__ data,
                                                  float* __restrict__ nodes,
                                                  bf16* __restrict__ embs_bf) {
  __shared__ float tile[32][33];
  int ct = blockIdx.x * 32, tt = blockIdx.y * 32;
  int bv = blockIdx.z;
  int b = bv / kV, v = bv - b * kV;
  int tx = threadIdx.x & 31, ty = threadIdx.x >> 5;
  for (int i = ty; i < 32; i += 8)
    tile[i][tx] = data[(((size_t)b * kC + ct + i) * kV + v) * kT + tt + tx];
  __syncthreads();
  for (int i = ty; i < 32; i += 8) {
    size_t s = (size_t)b * kT + tt + i;
    size_t idx = (s * kV + v) * kC + ct + tx;
    float val = tile[tx][i];
    nodes[idx] = val;
    embs_bf[idx] = __float2bfloat16(val);
  }
}

// final transpose fused with BN2-apply + leaky
__global__ __launch_bounds__(256) void k_xform_out(const float* __restrict__ Z,
                                                   const float* __restrict__ scale,
                                                   const float* __restrict__ shift,
                                                   float* __restrict__ out) {
  __shared__ float tile[32][33];
  int ct = blockIdx.x * 32, tt = blockIdx.y * 32;
  int bv = blockIdx.z;
  int b = bv / kV, v = bv - b * kV;
  int tx = threadIdx.x & 31, ty = threadIdx.x >> 5;
  float sc = scale[ct + tx], sh = shift[ct + tx];
  for (int i = ty; i < 32; i += 8) {
    size_t s = (size_t)b * kT + tt + i;
    float val = Z[(s * kV + v) * kC + ct + tx] * sc + sh;
    val = (val > 0.f) ? val : 0.01f * val;
    tile[i][tx] = val;
  }
  __syncthreads();
  for (int i = ty; i < 32; i += 8)
    out[(((size_t)b * kC + ct + i) * kV + v) * kT + tt + tx] = tile[tx][i];
}

// merged: layer-0 LN (blocks [0, kRows/4)) + relay0 init (rest).
// Both are independent consumers of nodes.
__global__ __launch_bounds__(256) void k_ln_relay(
    const float* __restrict__ nodes, const float* __restrict__ g,
    const float* __restrict__ b, float* __restrict__ O,
    bf16* __restrict__ Ob, bf16* __restrict__ relay0_bf) {
  int t = threadIdx.x;
  int bid = blockIdx.x;
  if (bid < kRows / 4) {
    int row = bid * 4 + (t >> 6);
    int c4 = (t & 63) * 4;
    size_t i = (size_t)row * kC + c4;
    float4 x = *(const float4*)(nodes + i);
    float s = x.x + x.y + x.z + x.w;
    float q = dot4(x, x);
#pragma unroll
    for (int o = 32; o >= 1; o >>= 1) {
      s += __shfl_xor(s, o);
      q += __shfl_xor(q, o);
    }
    float m = s * (1.f / 256.f);
    float var = q * (1.f / 256.f) - m * m;
    float rs = rsqrtf(var + 1e-6f);
    float4 g4 = *(const float4*)(g + c4);
    float4 b4 = *(const float4*)(b + c4);
    float4 o4 = make_float4((x.x - m) * rs * g4.x + b4.x,
                            (x.y - m) * rs * g4.y + b4.y,
                            (x.z - m) * rs * g4.z + b4.z,
                            (x.w - m) * rs * g4.w + b4.w);
    *(float4*)(O + i) = o4;
    stbf4(Ob + i, o4);
  } else {
    int s = (bid - kRows / 4) * 4 + (t >> 6);
    int c4 = (t & 63) * 4;
    float4 acc = make_float4(0.f, 0.f, 0.f, 0.f);
#pragma unroll
    for (int v = 0; v < kV; ++v) {
      float4 x = *(const float4*)(nodes + ((size_t)s * kV + v) * kC + c4);
      acc.x += x.x; acc.y += x.y; acc.z += x.z; acc.w += x.w;
    }
    float4 r =
        make_float4(acc.x / 17.f, acc.y / 17.f, acc.z / 17.f, acc.w / 17.f);
    stbf4(relay0_bf + (size_t)s * kC + c4, r);
  }
}

// satellite attention + fused BN1 partial stats (see round 13).
__global__ __launch_bounds__(256) void k_attn_sat(const bf16* __restrict__ qkv,
                                                  const bf16* __restrict__ akav,
                                                  float* __restrict__ z,
                                                  float* __restrict__ part,
                                                  int nb) {
  __shared__ float sS[4][256];
  __shared__ float qS[4][256];
  int t = threadIdx.x;
  int w = t >> 6;
  int rl = blockIdx.x * 4 + w;
  int lane = t & 63;
  int s = rl / kV, l = rl - s * kV;
  int c4 = lane * 4;
  float4 q = ldbf4(qkv + (size_t)rl * 768 + c4);
  int cnt = c_ncnt[l];
  float sc[7];
  int nrow[5];
#pragma unroll
  for (int wd = 0; wd < 5; ++wd) {
    nrow[wd] = s * kV + c_nbi[l][wd];
    float4 k = ldbf4(qkv + (size_t)nrow[wd] * 768 + 256 + c4);
    float p = dot4(q, k);
    p += __shfl_xor(p, 1, 8);
    p += __shfl_xor(p, 2, 8);
    p += __shfl_xor(p, 4, 8);
    sc[wd] = (wd < cnt) ? p * kInvSqrtDk : -1e30f;
  }
  {
    float4 k = ldbf4(akav + (size_t)rl * 1024 + c4);
    float p = dot4(q, k);
    p += __shfl_xor(p, 1, 8);
    p += __shfl_xor(p, 2, 8);
    p += __shfl_xor(p, 4, 8);
    sc[5] = p * kInvSqrtDk;
  }
  {
    float4 k = ldbf4(akav + (size_t)(kRows + s) * 1024 + c4);
    float p = dot4(q, k);
    p += __shfl_xor(p, 1, 8);
    p += __shfl_xor(p, 2, 8);
    p += __shfl_xor(p, 4, 8);
    sc[6] = p * kInvSqrtDk;
  }
  float mx = sc[0];
#pragma unroll
  for (int wd = 1; wd < 7; ++wd) mx = fmaxf(mx, sc[wd]);
  float den = 0.f;
#pragma unroll
  for (int wd = 0; wd < 7; ++wd) {
    sc[wd] = __expf(sc[wd] - mx);
    den += sc[wd];
  }
  float inv = 1.f / den;
  float4 acc = make_float4(0.f, 0.f, 0.f, 0.f);
#pragma unroll
  for (int wd = 0; wd < 5; ++wd) {
    float4 v = ldbf4(qkv + (size_t)nrow[wd] * 768 + 512 + c4);
    acc.x += sc[wd] * v.x; acc.y += sc[wd] * v.y;
    acc.z += sc[wd] * v.z; acc.w += sc[wd] * v.w;
  }
  {
    float4 v = ldbf4(akav + (size_t)rl * 1024 + 256 + c4);
    acc.x += sc[5] * v.x; acc.y += sc[5] * v.y;
    acc.z += sc[5] * v.z; acc.w += sc[5] * v.w;
  }
  {
    float4 v = ldbf4(akav + (size_t)(kRows + s) * 1024 + 256 + c4);
    acc.x += sc[6] * v.x; acc.y += sc[6] * v.y;
    acc.z += sc[6] * v.z; acc.w += sc[6] * v.w;
  }
  size_t zi = (size_t)rl * kC + c4;
  float4 xv = *(const float4*)(z + zi);
  float4 o = make_float4(xv.x + acc.x * inv, xv.y + acc.y * inv,
                         xv.z + acc.z * inv, xv.w + acc.w * inv);
  *(float4*)(z + zi) = o;
  sS[w][c4 + 0] = o.x; sS[w][c4 + 1] = o.y;
  sS[w][c4 + 2] = o.z; sS[w][c4 + 3] = o.w;
  qS[w][c4 + 0] = o.x * o.x; qS[w][c4 + 1] = o.y * o.y;
  qS[w][c4 + 2] = o.z * o.z; qS[w][c4 + 3] = o.w * o.w;
  __syncthreads();
  float ps = sS[0][t] + sS[1][t] + sS[2][t] + sS[3][t];
  float pq = qS[0][t] + qS[1][t] + qS[2][t] + qS[3][t];
  part[(size_t)blockIdx.x * kC + t] = ps;
  part[(size_t)(nb + blockIdx.x) * kC + t] = pq;
}

// BN stage 2: block per channel
__global__ __launch_bounds__(256) void k_bn_finalize(const float* __restrict__ part,
                                                     int nb, float inv_n,
                                                     const float* __restrict__ g,
                                                     const float* __restrict__ b,
                                                     float* __restrict__ scale,
                                                     float* __restrict__ shift) {
  int c = blockIdx.x;
  int t = threadIdx.x;
  float s = 0.f, q = 0.f;
  for (int i = t; i < nb; i += 256) {
    s += part[(size_t)i * kC + c];
    q += part[(size_t)(nb + i) * kC + c];
  }
#pragma unroll
  for (int o = 32; o >= 1; o >>= 1) {
    s += __shfl_xor(s, o);
    q += __shfl_xor(q, o);
  }
  __shared__ float ws[4], wq[4];
  int wid = t >> 6;
  if ((t & 63) == 0) { ws[wid] = s; wq[wid] = q; }
  __syncthreads();
  if (t == 0) {
    float S = ws[0] + ws[1] + ws[2] + ws[3];
    float Q = wq[0] + wq[1] + wq[2] + wq[3];
    float m = S * inv_n;
    float var = Q * inv_n - m * m;
    float sc = g[c] * rsqrtf(var + 1e-5f);
    scale[c] = sc;
    shift[c] = b[c] - m * sc;
  }
}

// BN stage 3: 4 rows/block, float4; writes fp32 and/or bf16
__global__ __launch_bounds__(256) void k_bn_apply(const float* __restrict__ Z,
                                                  const float* __restrict__ scale,
                                                  const float* __restrict__ shift,
                                                  float* __restrict__ outF,
                                                  bf16* __restrict__ outB,
                                                  int leaky) {
  int t = threadIdx.x;
  int row = blockIdx.x * 4 + (t >> 6);
  int c4 = (t & 63) * 4;
  size_t i = (size_t)row * kC + c4;
  float4 z = *(const float4*)(Z + i);
  float4 sc = *(const float4*)(scale + c4);
  float4 sh = *(const float4*)(shift + c4);
  float4 v = make_float4(z.x * sc.x + sh.x, z.y * sc.y + sh.y,
                         z.z * sc.z + sh.z, z.w * sc.w + sh.w);
  if (leaky) {
    v.x = (v.x > 0.f) ? v.x : 0.01f * v.x;
    v.y = (v.y > 0.f) ? v.y : 0.01f * v.y;
    v.z = (v.z > 0.f) ? v.z : 0.01f * v.z;
    v.w = (v.w > 0.f) ? v.w : 0.01f * v.w;
  }
  if (outF) *(float4*)(outF + i) = v;
  if (outB) stbf4(outB + i, v);
}

// Fused BN2(leaky)+LN at the layer boundary
__global__ __launch_bounds__(256) void k_bn_ln(
    const float* __restrict__ Z, const float* __restrict__ scale,
    const float* __restrict__ shift, const float* __restrict__ g,
    const float* __restrict__ b, float* __restrict__ xnOut,
    bf16* __restrict__ actOut) {
  int t = threadIdx.x;
  int row = blockIdx.x * 4 + (t >> 6);
  int c4 = (t & 63) * 4;
  size_t i = (size_t)row * kC + c4;
  float4 z = *(const float4*)(Z + i);
  float4 sc = *(const float4*)(scale + c4);
  float4 sh = *(const float4*)(shift + c4);
  float4 v = make_float4(z.x * sc.x + sh.x, z.y * sc.y + sh.y,
                         z.z * sc.z + sh.z, z.w * sc.w + sh.w);
  v.x = (v.x > 0.f) ? v.x : 0.01f * v.x;
  v.y = (v.y > 0.f) ? v.y : 0.01f * v.y;
  v.z = (v.z > 0.f) ? v.z : 0.01f * v.z;
  v.w = (v.w > 0.f) ? v.w : 0.01f * v.w;
  float s = v.x + v.y + v.z + v.w;
  float q = dot4(v, v);
#pragma unroll
  for (int o = 32; o >= 1; o >>= 1) {
    s += __shfl_xor(s, o);
    q += __shfl_xor(q, o);
  }
  float m = s * (1.f / 256.f);
  float var = q * (1.f / 256.f) - m * m;
  float rs = rsqrtf(var + 1e-6f);
  float4 g4 = *(const float4*)(g + c4);
  float4 b4 = *(const float4*)(b + c4);
  float4 o4 = make_float4((v.x - m) * rs * g4.x + b4.x,
                          (v.y - m) * rs * g4.y + b4.y,
                          (v.z - m) * rs * g4.z + b4.z,
                          (v.w - m) * rs * g4.w + b4.w);
  *(float4*)(xnOut + i) = o4;
  stbf4(actOut + i, o4);
}

// batched f32->bf16 conversion (12 chunks) + bias copies (10 x 256), one
// launch: blockIdx.y < 12 -> cvt; blockIdx.y == 12 -> bias copy.
struct CvtTab {
  const float* src[12];
  bf16* dst[12];
  int n[12];
  const float* bsrc[10];
  float* bdst[10];
};
__global__ __launch_bounds__(256) void k_cvt_multi(CvtTab t) {
  int c = blockIdx.y;
  if (c == 12) {
    if (blockIdx.x < 10) t.bdst[blockIdx.x][threadIdx.x] = t.bsrc[blockIdx.x][threadIdx.x];
    return;
  }
  int i = (blockIdx.x * 256 + threadIdx.x) * 4;
  if (i >= t.n[c]) return;
  float4 v = *(const float4*)(t.src[c] + i);
  stbf4(t.dst[c] + i, v);
}

extern "C" void kernel_launch(void* const* d_in, const int* in_sizes, int n_in,
                              void* d_out, int out_size, void* d_ws, size_t ws_size,
                              hipStream_t stream) {
  const float* data = (const float*)d_in[0];
  const float* ln_g = (const float*)d_in[1];
  const float* ln_b = (const float*)d_in[2];
  const float* jq_w = (const float*)d_in[3];
  const float* jq_b = (const float*)d_in[4];
  const float* jk_w = (const float*)d_in[5];
  const float* jk_b = (const float*)d_in[6];
  const float* jv_w = (const float*)d_in[7];
  const float* jv_b = (const float*)d_in[8];
  const float* jbn_g = (const float*)d_in[9];
  const float* jbn_b = (const float*)d_in[10];
  const float* jf1_w = (const float*)d_in[11];
  const float* jf1_b = (const float*)d_in[12];
  const float* jf2_w = (const float*)d_in[13];
  const float* jf2_b = (const float*)d_in[14];
  const float* jfbn_g = (const float*)d_in[15];
  const float* jfbn_b = (const float*)d_in[16];
  // d_in[17..30]: relay-branch weights — dead code, unused.
  float* out = (float*)d_out;

  // ---- arena ----
  float* f = (float*)d_ws;
  float* nodes = f;    f += SZ_BIG;
  float* xn = f;       f += SZ_BIG;           // LN out -> z -> y2
  float* part = f;     f += 2 * (kRows / 4) * kC;  // BN partials (nb<=4352)
  float* scale = f;    f += kC;
  float* shift = f;    f += kC;
  float* cb_jqkv = f;  f += 2 * 768;
  float* cb_kv4 = f;   f += 1024;

  bf16* bfa = (bf16*)f;
  bf16* act_bf = bfa;   bfa += SZ_BIG;                 // 17408 x 256
  bf16* embsX_bf = bfa; bfa += (size_t)kRowsE * kC;    // [embs; relay0]
  bf16* P = bfa;        bfa += (size_t)kRows * kDIN;   // qkv (768) / h (1024)
  bf16* akavBuf = bfa;  bfa += (size_t)kRowsE * 1024;  // [k0|v0|k1|v1]
  bf16* Wjqkv = bfa;    bfa += 2 * 768 * 256;
  bf16* Wkv4 = bfa;     bfa += 1024 * 256;
  bf16* Wjf1 = bfa;     bfa += 2 * 1024 * 256;
  bf16* Wjf2 = bfa;     bfa += 2 * 256 * 1024;

  bf16* relay0_bf = embsX_bf + SZ_BIG;  // rows kRows..kRowsE-1
  bf16* qkv_bf = P;                     // 17408 x 768
  bf16* h_bf = P;                       // 17408 x 1024
  float* y2 = xn;

  auto gemm = [&](const bf16* A, const bf16* W, const float* bias,
                  bf16* oB, int M, int N, int flags) {
    dim3 g(M / 128, N / 128);
    k_mfma_gemm<256><<<g, 256, 0, stream>>>(A, W, bias, oB, N, flags);
  };

  // ---- weight conversion + bias copies (one launch) ----
  {
    CvtTab t;
    for (int i = 0; i < 2; ++i) {
      const size_t om = (size_t)i * kC * kC;
      const float* s3[3] = {jq_w + om, jk_w + om, jv_w + om};
      bf16* d3[3] = {Wjqkv + (size_t)i * 768 * 256,
                     Wjqkv + (size_t)i * 768 * 256 + 65536,
                     Wjqkv + (size_t)i * 768 * 256 + 131072};
      for (int j = 0; j < 3; ++j) {
        t.src[i * 3 + j] = s3[j];
        t.dst[i * 3 + j] = d3[j];
        t.n[i * 3 + j] = 65536;
      }
    }
    // Wkv4 = [k0 | v0 | k1 | v1]
    t.src[6] = jk_w;                 t.dst[6] = Wkv4;               t.n[6] = 65536;
    t.src[7] = jv_w;                 t.dst[7] = Wkv4 + 65536;       t.n[7] = 65536;
    t.src[8] = jk_w + (size_t)65536; t.dst[8] = Wkv4 + 131072;      t.n[8] = 65536;
    t.src[9] = jv_w + (size_t)65536; t.dst[9] = Wkv4 + 196608;      t.n[9] = 65536;
    t.src[10] = jf1_w; t.dst[10] = Wjf1; t.n[10] = 2 * 1024 * 256;
    t.src[11] = jf2_w; t.dst[11] = Wjf2; t.n[11] = 2 * 256 * 1024;
    for (int i = 0; i < 2; ++i) {
      t.bsrc[i * 3 + 0] = jq_b + (size_t)i * kC;
      t.bsrc[i * 3 + 1] = jk_b + (size_t)i * kC;
      t.bsrc[i * 3 + 2] = jv_b + (size_t)i * kC;
      t.bdst[i * 3 + 0] = cb_jqkv + i * 768;
      t.bdst[i * 3 + 1] = cb_jqkv + i * 768 + 256;
      t.bdst[i * 3 + 2] = cb_jqkv + i * 768 + 512;
    }
    t.bsrc[6] = jk_b;       t.bdst[6] = cb_kv4;
    t.bsrc[7] = jv_b;       t.bdst[7] = cb_kv4 + 256;
    t.bsrc[8] = jk_b + kC;  t.bdst[8] = cb_kv4 + 512;
    t.bsrc[9] = jv_b + kC;  t.bdst[9] = cb_kv4 + 768;
    k_cvt_multi<<<dim3(512, 13), 256, 0, stream>>>(t);
  }

  k_xform_in<<<dim3(8, 8, 4 * kV), 256, 0, stream>>>(data, nodes, embsX_bf);

  // merged layer-0 LN + relay0 init (both consume nodes)
  k_ln_relay<<<kRows / 4 + kBT / 4, 256, 0, stream>>>(nodes, ln_g, ln_b, xn,
                                                      act_bf, relay0_bf);

  // dual launch: hoisted KV projections (both layers) + layer-0 qkv.
  // GEMM0: [embs;relay0](18432) x Wkv4(1024)  -> akavBuf   (1152 blocks)
  // GEMM1: act_bf(17408)        x Wjqkv0(768) -> qkv_bf    ( 816 blocks)
  {
    const int gx0 = kRowsE / 128, nb0 = gx0 * (1024 / 128);  // 144*8=1152
    const int gx1 = kRows / 128, nb1 = gx1 * (768 / 128);    // 136*6=816
    k_mfma_gemm_dual<<<nb0 + nb1, 256, 0, stream>>>(
        embsX_bf, Wkv4, cb_kv4, akavBuf, 1024, gx0, nb0,
        act_bf, Wjqkv, cb_jqkv, qkv_bf, 768, gx1);
  }

  for (int i = 0; i < 2; ++i) {
    const size_t ob = (size_t)i * kC, ofb1 = (size_t)i * kDIN;
    const bf16* Wf1 = Wjf1 + (size_t)i * 1024 * 256;
    const bf16* Wf2 = Wjf2 + (size_t)i * 256 * 1024;
    const int nbA = kRows / 4;    // attn-fused BN1 partials
    const int nbG = kRows / 64;   // f2-64-fused BN2 partials (272)

    if (i == 1) {
      // layer-1 qkv (layer-0 qkv was in the dual launch)
      gemm(act_bf, Wjqkv + (size_t)768 * 256, cb_jqkv + 768, qkv_bf, kRows,
           768, 4);
    }
    // z = xn + att; fused BN1 partial stats
    k_attn_sat<<<kRows / 4, 256, 0, stream>>>(qkv_bf, akavBuf + (size_t)i * 512,
                                              xn, part, nbA);
    k_bn_finalize<<<kC, 256, 0, stream>>>(part, nbA, 1.f / kRows, jbn_g + ob,
                                          jbn_b + ob, scale, shift);
    // BN1 apply -> act_bf only (fp32 residual applied on the fly in f2)
    k_bn_apply<<<kRows / 4, 256, 0, stream>>>(xn, scale, shift, nullptr,
                                              act_bf, 0);
    gemm(act_bf, Wf1, jf1_b + ofb1, h_bf, kRows, 1024, 4 | 1);
    // f2 (64x64 tiles): y2 = h@Wf2 + b + (xn*scale+shift); BN2 partials.
    k_mfma_gemm64<<<dim3(kRows / 64, kC / 64), 256, 0, stream>>>(
        h_bf, Wf2, jf2_b + ob, xn, y2, scale, shift, part, nbG, kC);
    k_bn_finalize<<<kC, 256, 0, stream>>>(part, nbG, 1.f / kRows, jfbn_g + ob,
                                          jfbn_b + ob, scale, shift);
    if (i == 0) {
      // fused BN2(leaky) + layer-1 LN (reads y2, writes xn + act_bf)
      k_bn_ln<<<kRows / 4, 256, 0, stream>>>(y2, scale, shift, ln_g + kC,
                                             ln_b + kC, xn, act_bf);
    }
    // i == 1: BN2 apply + leaky fused into k_xform_out below.
  }

  k_xform_out<<<dim3(8, 8, 4 * kV), 256, 0, stream>>>(y2, scale, shift, out);
  (void)in_sizes; (void)n_in; (void)out_size; (void)ws_size;
}

// Round 15
// 374.841 us; speedup vs baseline: 1.1871x; 1.0559x over previous
//
#include <hip/hip_runtime.h>
#include <hip/hip_bf16.h>

// ---------------------------------------------------------------------------
// Star-Transformer 2-layer forward — satellite branch only (relay chain is
// dead code for the output, established round 10).
// Round 26: r25 base (best: 395.8us) + attn BN1-partial widening: k_attn_sat
// now 16 rows/block (4 waves x 4 rows, per-lane register accumulation of
// sum/sumsq across each wave's rows, same cross-wave LDS combine) ->
// part traffic drops 4x (8.9->2.2 MB per direction per layer, ~27MB total
// saved), k_bn_finalize loops 4352->1088, and each wave gets 4 independent
// rows of loads to overlap. Per-element arithmetic unchanged; partial
// regrouping only reassociates (same class as r13/r19 nb changes).
// Locked config: 128^2 BK=32-dbuf K=256 GEMMs @4 blocks/CU (design lattice
// closed: BK{32,64,128,fullK} x tile{64^2,128^2} x staging{LDS,reg} x
// sync{barrier,counted-vmcnt} all bracketed); f2 64x64 BK=64 @4.25
// blocks/CU (r19 -26us); k_ln_relay merge + dual-launch (r23 -8us); r13
// fusion set (BN1 stats in attn, BN2 stats + BN1-residual in f2 epilogue,
// BN2+leaky in final transpose, BN2+LN at layer boundary); bf16 C-repack
// through LDS; hoisted [embs;relay0] K/V projections.
// Row-major activations (row, channel), C=256 contiguous.
// ---------------------------------------------------------------------------

using bf16 = __hip_bfloat16;
typedef __attribute__((ext_vector_type(8))) short bf16x8v;
typedef __attribute__((ext_vector_type(4))) float f32x4;

namespace {
constexpr int kBT = 1024;
constexpr int kC = 256;
constexpr int kV = 17;
constexpr int kT = 256;
constexpr int kDIN = 1024;
constexpr int kRows = kBT * kV;                  // 17408
constexpr int kRowsE = kRows + kBT;              // 18432 = embs + relay0
constexpr float kInvSqrtDk = 0.17677669529663687f;
constexpr size_t SZ_BIG = (size_t)kRows * kC;
}  // namespace

__constant__ int c_nbi[17][5] = {
    {0, 1, 2, 5, 6},   {0, 1, 3, 0, 0},   {0, 2, 4, 0, 0},  {1, 3, 0, 0, 0},
    {2, 4, 0, 0, 0},   {0, 5, 7, 11, 0},  {0, 6, 8, 12, 0}, {5, 7, 9, 0, 0},
    {6, 8, 12, 0, 0},  {7, 9, 0, 0, 0},   {8, 10, 0, 0, 0}, {8, 11, 13, 0, 0},
    {10, 12, 14, 0, 0},{11, 13, 15, 0, 0},{12, 14, 16, 0, 0},
    {13, 15, 0, 0, 0}, {14, 16, 0, 0, 0}};
__constant__ int c_ncnt[17] = {5, 3, 3, 2, 2, 4, 4, 3, 3, 2, 2, 3, 3, 3, 3, 2, 2};

__device__ inline float bf2f(unsigned short s) {
  unsigned int u = ((unsigned int)s) << 16;
  float f;
  __builtin_memcpy(&f, &u, 4);
  return f;
}
__device__ inline unsigned short f2bf(float f) {
  unsigned int u;
  __builtin_memcpy(&u, &f, 4);
  unsigned int r = (u + 0x7fffu + ((u >> 16) & 1u)) >> 16;  // RNE
  return (unsigned short)r;
}
__device__ inline float4 ldbf4(const bf16* p) {
  ushort4 u = *(const ushort4*)p;
  return make_float4(bf2f(u.x), bf2f(u.y), bf2f(u.z), bf2f(u.w));
}
__device__ inline void stbf4(bf16* p, float4 v) {
  ushort4 u = make_ushort4(f2bf(v.x), f2bf(v.y), f2bf(v.z), f2bf(v.w));
  *(ushort4*)p = u;
}
__device__ inline float dot4(float4 a, float4 b) {
  return a.x * b.x + a.y * b.y + a.z * b.z + a.w * b.w;
}

__device__ inline void async16(const bf16* g, bf16* l) {
  __builtin_amdgcn_global_load_lds(
      (const __attribute__((address_space(1))) void*)g,
      (__attribute__((address_space(3))) void*)l, 16, 0, 0);
}

// ---- shared 128x128-tile GEMM body (K=256), bf16-out path ----
// BK=32 double-buffered; 32 KB LDS arena -> 4 blocks/CU.
template <int KT>
__device__ __forceinline__ void gemm128_body(
    char* smem_raw, const bf16* __restrict__ A, const bf16* __restrict__ W,
    const float* __restrict__ bias, bf16* __restrict__ outB, int N, int flags,
    int row0, int col0) {
  bf16* As = (bf16*)smem_raw;              // 2 x 4096 elems (16 KB)
  bf16* Bs = (bf16*)(smem_raw + 16384);    // 2 x 4096 elems (16 KB)
  const int tid = threadIdx.x;
  const int wave = tid >> 6;
  const int lane = tid & 63;

  const int sub = lane >> 2;
  const int kq = (lane & 3) * 8;
  const int rg0 = (2 * wave + 0) * 16;
  const int rg1 = (2 * wave + 1) * 16;
  const bf16* ag0 = A + (size_t)(row0 + rg0 + sub) * KT + kq;
  const bf16* ag1 = A + (size_t)(row0 + rg1 + sub) * KT + kq;
  const bf16* bg0 = W + (size_t)(col0 + rg0 + sub) * KT + kq;
  const bf16* bg1 = W + (size_t)(col0 + rg1 + sub) * KT + kq;

  const int wm = wave >> 1, wn = wave & 1;
  const int fr = lane & 15;
  const int fk = (lane >> 4) * 8;

  f32x4 acc[4][4];
#pragma unroll
  for (int i = 0; i < 4; ++i)
#pragma unroll
    for (int j = 0; j < 4; ++j) acc[i][j] = (f32x4){0.f, 0.f, 0.f, 0.f};

#define STAGE32(buf, koff)                              \
  do {                                                  \
    async16(ag0 + (koff), As + (buf) * 4096 + rg0 * 32); \
    async16(ag1 + (koff), As + (buf) * 4096 + rg1 * 32); \
    async16(bg0 + (koff), Bs + (buf) * 4096 + rg0 * 32); \
    async16(bg1 + (koff), Bs + (buf) * 4096 + rg1 * 32); \
  } while (0)

  STAGE32(0, 0);
  __syncthreads();  // buf0 ready

  for (int k0 = 0; k0 < KT; k0 += 32) {
    const int cur = (k0 >> 5) & 1;
    if (k0 + 32 < KT) STAGE32(cur ^ 1, k0 + 32);  // in flight during MFMA
    bf16x8v af[4], bfv[4];
#pragma unroll
    for (int i = 0; i < 4; ++i)
      af[i] = *(const bf16x8v*)&As[cur * 4096 +
                                   (wm * 64 + i * 16 + fr) * 32 + fk];
#pragma unroll
    for (int j = 0; j < 4; ++j)
      bfv[j] = *(const bf16x8v*)&Bs[cur * 4096 +
                                    (wn * 64 + j * 16 + fr) * 32 + fk];
#pragma unroll
    for (int i = 0; i < 4; ++i)
#pragma unroll
      for (int j = 0; j < 4; ++j)
        acc[i][j] = __builtin_amdgcn_mfma_f32_16x16x32_bf16(af[i], bfv[j],
                                                            acc[i][j], 0, 0,
                                                            0);
    __syncthreads();
  }
#undef STAGE32

  // bf16 out: stage C-tile in LDS (ushort 128x128 = 32 KB arena), then
  // 8 passes of 16 rows x 256B fully-coalesced stores.
  unsigned short* cs = (unsigned short*)smem_raw;
#pragma unroll
  for (int j = 0; j < 4; ++j) {
    int lc = wn * 64 + j * 16 + fr;
    float bv = bias ? bias[col0 + lc] : 0.f;
#pragma unroll
    for (int i = 0; i < 4; ++i) {
      int lr = wm * 64 + i * 16 + (lane >> 4) * 4;
#pragma unroll
      for (int r = 0; r < 4; ++r) {
        float v = acc[i][j][r] + bv;
        if (flags & 1) v = fmaxf(v, 0.f);
        cs[(lr + r) * 128 + lc] = f2bf(v);
      }
    }
  }
  __syncthreads();
#pragma unroll
  for (int p = 0; p < 8; ++p) {
    int lr = p * 16 + (tid >> 4);
    int lc = (tid & 15) * 8;
    *(bf16x8v*)&outB[(size_t)(row0 + lr) * N + col0 + lc] =
        *(const bf16x8v*)&cs[lr * 128 + lc];
  }
}

// ---- single GEMM launch (K=256) ----
template <int KT>
__global__ __launch_bounds__(256, 4) void k_mfma_gemm(
    const bf16* __restrict__ A, const bf16* __restrict__ W,
    const float* __restrict__ bias, bf16* __restrict__ outB, int N,
    int flags) {
  __shared__ __align__(16) char smem_raw[32768];
  gemm128_body<KT>(smem_raw, A, W, bias, outB, N, flags, blockIdx.x * 128,
                   blockIdx.y * 128);
}

// ---- dual GEMM launch: two independent K=256 bf16-out GEMMs in one grid.
// Blocks [0, nb0) run GEMM0 (gx0 row-tiles fastest); rest run GEMM1.
__global__ __launch_bounds__(256, 4) void k_mfma_gemm_dual(
    const bf16* __restrict__ A0, const bf16* __restrict__ W0,
    const float* __restrict__ b0, bf16* __restrict__ o0, int N0, int gx0,
    int nb0, const bf16* __restrict__ A1, const bf16* __restrict__ W1,
    const float* __restrict__ b1, bf16* __restrict__ o1, int N1, int gx1) {
  __shared__ __align__(16) char smem_raw[32768];
  const int bid = blockIdx.x;
  if (bid < nb0) {
    int bx = bid % gx0, by = bid / gx0;
    gemm128_body<256>(smem_raw, A0, W0, b0, o0, N0, 4, bx * 128, by * 128);
  } else {
    int local = bid - nb0;
    int bx = local % gx1, by = local / gx1;
    gemm128_body<256>(smem_raw, A1, W1, b1, o1, N1, 4, bx * 128, by * 128);
  }
}

// ---- f2-dedicated 64x64-tile GEMM: KT=1024, fp32 out, BN1-residual apply
// + BN2 partial stats. Grid (M/64, N/64) = 1088 blocks -> ~4 blocks/CU.
__global__ __launch_bounds__(256, 4) void k_mfma_gemm64(
    const bf16* __restrict__ A, const bf16* __restrict__ W,
    const float* __restrict__ bias, const float* __restrict__ res,
    float* __restrict__ outF, const float* __restrict__ bnScI,
    const float* __restrict__ bnShI, float* __restrict__ partOut, int nbPart,
    int N) {
  constexpr int KT = 1024;
  __shared__ __align__(16) bf16 As[2][4096];  // 2 x (2 chunks x 64 x 32)
  __shared__ __align__(16) bf16 Bs[2][4096];
  __shared__ float sred[4 * 64];
  __shared__ float qred[4 * 64];
  const int tid = threadIdx.x;
  const int wave = tid >> 6;
  const int lane = tid & 63;
  const int row0 = blockIdx.x * 64;
  const int col0 = blockIdx.y * 64;

  // global src per-lane: row wave*16 + (lane>>2), cols (lane&3)*8..+7
  const int srow = wave * 16 + (lane >> 2);
  const int skq = (lane & 3) * 8;
  const bf16* ag = A + (size_t)(row0 + srow) * KT + skq;
  const bf16* bg = W + (size_t)(col0 + srow) * KT + skq;

  const int wm = wave >> 1, wn = wave & 1;
  const int fr = lane & 15;
  const int fk = (lane >> 4) * 8;

  f32x4 acc[2][2];
#pragma unroll
  for (int i = 0; i < 2; ++i)
#pragma unroll
    for (int j = 0; j < 2; ++j) acc[i][j] = (f32x4){0.f, 0.f, 0.f, 0.f};

  // LDS dest: wave-uniform base; HW scatters lane i at +16B*i.
#define STAGE64x64(buf, koff)                                      \
  do {                                                             \
    _Pragma("unroll") for (int kc = 0; kc < 2; ++kc) {             \
      async16(ag + (koff) + kc * 32,                               \
              &As[(buf)][kc * 2048 + wave * 512]);                 \
      async16(bg + (koff) + kc * 32,                               \
              &Bs[(buf)][kc * 2048 + wave * 512]);                 \
    }                                                              \
  } while (0)

  STAGE64x64(0, 0);
  __syncthreads();

  for (int k0 = 0; k0 < KT; k0 += 64) {
    const int cur = (k0 >> 6) & 1;
    if (k0 + 64 < KT) STAGE64x64(cur ^ 1, k0 + 64);
#pragma unroll
    for (int kc = 0; kc < 2; ++kc) {
      bf16x8v af[2], bfv[2];
#pragma unroll
      for (int i = 0; i < 2; ++i)
        af[i] = *(const bf16x8v*)&As[cur][kc * 2048 +
                                          (wm * 32 + i * 16 + fr) * 32 + fk];
#pragma unroll
      for (int j = 0; j < 2; ++j)
        bfv[j] = *(const bf16x8v*)&Bs[cur][kc * 2048 +
                                           (wn * 32 + j * 16 + fr) * 32 + fk];
#pragma unroll
      for (int i = 0; i < 2; ++i)
#pragma unroll
        for (int j = 0; j < 2; ++j)
          acc[i][j] = __builtin_amdgcn_mfma_f32_16x16x32_bf16(af[i], bfv[j],
                                                              acc[i][j], 0, 0,
                                                              0);
    }
    __syncthreads();
  }
#undef STAGE64x64

  // fp32 epilogue: out = acc + bias + res*bnSc + bnSh; BN2 partial stats.
  const int crow = row0 + wm * 32;
  const int ccol = col0 + wn * 32;
  float colS[2] = {0.f, 0.f};
  float colQ[2] = {0.f, 0.f};
#pragma unroll
  for (int j = 0; j < 2; ++j) {
    int col = ccol + j * 16 + fr;
    float bv = bias[col];
    float rsc = bnScI[col], rsh = bnShI[col];
#pragma unroll
    for (int i = 0; i < 2; ++i) {
      int rowb = crow + i * 16 + (lane >> 4) * 4;
#pragma unroll
      for (int r = 0; r < 4; ++r) {
        size_t row = (size_t)(rowb + r);
        float v = acc[i][j][r] + bv + res[row * N + col] * rsc + rsh;
        outF[row * N + col] = v;
        colS[j] += v;
        colQ[j] += v * v;
      }
    }
  }
  // reduce the 4 row-groups within the wave (lane bit4, bit5)
#pragma unroll
  for (int j = 0; j < 2; ++j) {
    colS[j] += __shfl_xor(colS[j], 16);
    colS[j] += __shfl_xor(colS[j], 32);
    colQ[j] += __shfl_xor(colQ[j], 16);
    colQ[j] += __shfl_xor(colQ[j], 32);
  }
  if (lane < 16) {
#pragma unroll
    for (int j = 0; j < 2; ++j) {
      sred[wave * 64 + j * 16 + fr] = colS[j];
      qred[wave * 64 + j * 16 + fr] = colQ[j];
    }
  }
  __syncthreads();
  if (tid < 64) {
    int c = tid;
    int wsel = c >> 5, off = c & 31;
    float s = sred[wsel * 64 + off] + sred[(wsel + 2) * 64 + off];
    float q = qred[wsel * 64 + off] + qred[(wsel + 2) * 64 + off];
    int col = col0 + c;
    partOut[(size_t)blockIdx.x * kC + col] = s;
    partOut[(size_t)(nbPart + blockIdx.x) * kC + col] = q;
  }
}

// data (B,C,V,T) -> nodes fp32 rows + embs bf16 rows
__global__ __launch_bounds__(256) void k_xform_in(const float* __restrict__ data,
                                                  float* __restrict__ nodes,
                                                  bf16* __restrict__ embs_bf) {
  __shared__ float tile[32][33];
  int ct = blockIdx.x * 32, tt = blockIdx.y * 32;
  int bv = blockIdx.z;
  int b = bv / kV, v = bv - b * kV;
  int tx = threadIdx.x & 31, ty = threadIdx.x >> 5;
  for (int i = ty; i < 32; i += 8)
    tile[i][tx] = data[(((size_t)b * kC + ct + i) * kV + v) * kT + tt + tx];
  __syncthreads();
  for (int i = ty; i < 32; i += 8) {
    size_t s = (size_t)b * kT + tt + i;
    size_t idx = (s * kV + v) * kC + ct + tx;
    float val = tile[tx][i];
    nodes[idx] = val;
    embs_bf[idx] = __float2bfloat16(val);
  }
}

// final transpose fused with BN2-apply + leaky
__global__ __launch_bounds__(256) void k_xform_out(const float* __restrict__ Z,
                                                   const float* __restrict__ scale,
                                                   const float* __restrict__ shift,
                                                   float* __restrict__ out) {
  __shared__ float tile[32][33];
  int ct = blockIdx.x * 32, tt = blockIdx.y * 32;
  int bv = blockIdx.z;
  int b = bv / kV, v = bv - b * kV;
  int tx = threadIdx.x & 31, ty = threadIdx.x >> 5;
  float sc = scale[ct + tx], sh = shift[ct + tx];
  for (int i = ty; i < 32; i += 8) {
    size_t s = (size_t)b * kT + tt + i;
    float val = Z[(s * kV + v) * kC + ct + tx] * sc + sh;
    val = (val > 0.f) ? val : 0.01f * val;
    tile[i][tx] = val;
  }
  __syncthreads();
  for (int i = ty; i < 32; i += 8)
    out[(((size_t)b * kC + ct + i) * kV + v) * kT + tt + tx] = tile[tx][i];
}

// merged: layer-0 LN (blocks [0, kRows/4)) + relay0 init (rest).
// Both are independent consumers of nodes.
__global__ __launch_bounds__(256) void k_ln_relay(
    const float* __restrict__ nodes, const float* __restrict__ g,
    const float* __restrict__ b, float* __restrict__ O,
    bf16* __restrict__ Ob, bf16* __restrict__ relay0_bf) {
  int t = threadIdx.x;
  int bid = blockIdx.x;
  if (bid < kRows / 4) {
    int row = bid * 4 + (t >> 6);
    int c4 = (t & 63) * 4;
    size_t i = (size_t)row * kC + c4;
    float4 x = *(const float4*)(nodes + i);
    float s = x.x + x.y + x.z + x.w;
    float q = dot4(x, x);
#pragma unroll
    for (int o = 32; o >= 1; o >>= 1) {
      s += __shfl_xor(s, o);
      q += __shfl_xor(q, o);
    }
    float m = s * (1.f / 256.f);
    float var = q * (1.f / 256.f) - m * m;
    float rs = rsqrtf(var + 1e-6f);
    float4 g4 = *(const float4*)(g + c4);
    float4 b4 = *(const float4*)(b + c4);
    float4 o4 = make_float4((x.x - m) * rs * g4.x + b4.x,
                            (x.y - m) * rs * g4.y + b4.y,
                            (x.z - m) * rs * g4.z + b4.z,
                            (x.w - m) * rs * g4.w + b4.w);
    *(float4*)(O + i) = o4;
    stbf4(Ob + i, o4);
  } else {
    int s = (bid - kRows / 4) * 4 + (t >> 6);
    int c4 = (t & 63) * 4;
    float4 acc = make_float4(0.f, 0.f, 0.f, 0.f);
#pragma unroll
    for (int v = 0; v < kV; ++v) {
      float4 x = *(const float4*)(nodes + ((size_t)s * kV + v) * kC + c4);
      acc.x += x.x; acc.y += x.y; acc.z += x.z; acc.w += x.w;
    }
    float4 r =
        make_float4(acc.x / 17.f, acc.y / 17.f, acc.z / 17.f, acc.w / 17.f);
    stbf4(relay0_bf + (size_t)s * kC + c4, r);
  }
}

// satellite attention + fused BN1 partial stats. 16 rows/block: 4 waves x
// 4 rows each (serial per wave, register-accumulated sum/sumsq), then the
// cross-wave LDS combine -> part rows = kRows/16 = 1088 (4x less traffic).
__global__ __launch_bounds__(256) void k_attn_sat(const bf16* __restrict__ qkv,
                                                  const bf16* __restrict__ akav,
                                                  float* __restrict__ z,
                                                  float* __restrict__ part,
                                                  int nb) {
  __shared__ float sS[4][256];
  __shared__ float qS[4][256];
  int t = threadIdx.x;
  int w = t >> 6;
  int lane = t & 63;
  int c4 = lane * 4;
  float sAcc[4] = {0.f, 0.f, 0.f, 0.f};
  float qAcc[4] = {0.f, 0.f, 0.f, 0.f};
  for (int r = 0; r < 4; ++r) {
    int rl = blockIdx.x * 16 + w * 4 + r;
    int s = rl / kV, l = rl - s * kV;
    float4 q = ldbf4(qkv + (size_t)rl * 768 + c4);
    int cnt = c_ncnt[l];
    float sc[7];
    int nrow[5];
#pragma unroll
    for (int wd = 0; wd < 5; ++wd) {
      nrow[wd] = s * kV + c_nbi[l][wd];
      float4 k = ldbf4(qkv + (size_t)nrow[wd] * 768 + 256 + c4);
      float p = dot4(q, k);
      p += __shfl_xor(p, 1, 8);
      p += __shfl_xor(p, 2, 8);
      p += __shfl_xor(p, 4, 8);
      sc[wd] = (wd < cnt) ? p * kInvSqrtDk : -1e30f;
    }
    {
      float4 k = ldbf4(akav + (size_t)rl * 1024 + c4);
      float p = dot4(q, k);
      p += __shfl_xor(p, 1, 8);
      p += __shfl_xor(p, 2, 8);
      p += __shfl_xor(p, 4, 8);
      sc[5] = p * kInvSqrtDk;
    }
    {
      float4 k = ldbf4(akav + (size_t)(kRows + s) * 1024 + c4);
      float p = dot4(q, k);
      p += __shfl_xor(p, 1, 8);
      p += __shfl_xor(p, 2, 8);
      p += __shfl_xor(p, 4, 8);
      sc[6] = p * kInvSqrtDk;
    }
    float mx = sc[0];
#pragma unroll
    for (int wd = 1; wd < 7; ++wd) mx = fmaxf(mx, sc[wd]);
    float den = 0.f;
#pragma unroll
    for (int wd = 0; wd < 7; ++wd) {
      sc[wd] = __expf(sc[wd] - mx);
      den += sc[wd];
    }
    float inv = 1.f / den;
    float4 acc = make_float4(0.f, 0.f, 0.f, 0.f);
#pragma unroll
    for (int wd = 0; wd < 5; ++wd) {
      float4 v = ldbf4(qkv + (size_t)nrow[wd] * 768 + 512 + c4);
      acc.x += sc[wd] * v.x; acc.y += sc[wd] * v.y;
      acc.z += sc[wd] * v.z; acc.w += sc[wd] * v.w;
    }
    {
      float4 v = ldbf4(akav + (size_t)rl * 1024 + 256 + c4);
      acc.x += sc[5] * v.x; acc.y += sc[5] * v.y;
      acc.z += sc[5] * v.z; acc.w += sc[5] * v.w;
    }
    {
      float4 v = ldbf4(akav + (size_t)(kRows + s) * 1024 + 256 + c4);
      acc.x += sc[6] * v.x; acc.y += sc[6] * v.y;
      acc.z += sc[6] * v.z; acc.w += sc[6] * v.w;
    }
    size_t zi = (size_t)rl * kC + c4;
    float4 xv = *(const float4*)(z + zi);
    float4 o = make_float4(xv.x + acc.x * inv, xv.y + acc.y * inv,
                           xv.z + acc.z * inv, xv.w + acc.w * inv);
    *(float4*)(z + zi) = o;
    sAcc[0] += o.x; sAcc[1] += o.y; sAcc[2] += o.z; sAcc[3] += o.w;
    qAcc[0] += o.x * o.x; qAcc[1] += o.y * o.y;
    qAcc[2] += o.z * o.z; qAcc[3] += o.w * o.w;
  }
  sS[w][c4 + 0] = sAcc[0]; sS[w][c4 + 1] = sAcc[1];
  sS[w][c4 + 2] = sAcc[2]; sS[w][c4 + 3] = sAcc[3];
  qS[w][c4 + 0] = qAcc[0]; qS[w][c4 + 1] = qAcc[1];
  qS[w][c4 + 2] = qAcc[2]; qS[w][c4 + 3] = qAcc[3];
  __syncthreads();
  float ps = sS[0][t] + sS[1][t] + sS[2][t] + sS[3][t];
  float pq = qS[0][t] + qS[1][t] + qS[2][t] + qS[3][t];
  part[(size_t)blockIdx.x * kC + t] = ps;
  part[(size_t)(nb + blockIdx.x) * kC + t] = pq;
}

// BN stage 2: block per channel
__global__ __launch_bounds__(256) void k_bn_finalize(const float* __restrict__ part,
                                                     int nb, float inv_n,
                                                     const float* __restrict__ g,
                                                     const float* __restrict__ b,
                                                     float* __restrict__ scale,
                                                     float* __restrict__ shift) {
  int c = blockIdx.x;
  int t = threadIdx.x;
  float s = 0.f, q = 0.f;
  for (int i = t; i < nb; i += 256) {
    s += part[(size_t)i * kC + c];
    q += part[(size_t)(nb + i) * kC + c];
  }
#pragma unroll
  for (int o = 32; o >= 1; o >>= 1) {
    s += __shfl_xor(s, o);
    q += __shfl_xor(q, o);
  }
  __shared__ float ws[4], wq[4];
  int wid = t >> 6;
  if ((t & 63) == 0) { ws[wid] = s; wq[wid] = q; }
  __syncthreads();
  if (t == 0) {
    float S = ws[0] + ws[1] + ws[2] + ws[3];
    float Q = wq[0] + wq[1] + wq[2] + wq[3];
    float m = S * inv_n;
    float var = Q * inv_n - m * m;
    float sc = g[c] * rsqrtf(var + 1e-5f);
    scale[c] = sc;
    shift[c] = b[c] - m * sc;
  }
}

// BN stage 3: 4 rows/block, float4; writes fp32 and/or bf16
__global__ __launch_bounds__(256) void k_bn_apply(const float* __restrict__ Z,
                                                  const float* __restrict__ scale,
                                                  const float* __restrict__ shift,
                                                  float* __restrict__ outF,
                                                  bf16* __restrict__ outB,
                                                  int leaky) {
  int t = threadIdx.x;
  int row = blockIdx.x * 4 + (t >> 6);
  int c4 = (t & 63) * 4;
  size_t i = (size_t)row * kC + c4;
  float4 z = *(const float4*)(Z + i);
  float4 sc = *(const float4*)(scale + c4);
  float4 sh = *(const float4*)(shift + c4);
  float4 v = make_float4(z.x * sc.x + sh.x, z.y * sc.y + sh.y,
                         z.z * sc.z + sh.z, z.w * sc.w + sh.w);
  if (leaky) {
    v.x = (v.x > 0.f) ? v.x : 0.01f * v.x;
    v.y = (v.y > 0.f) ? v.y : 0.01f * v.y;
    v.z = (v.z > 0.f) ? v.z : 0.01f * v.z;
    v.w = (v.w > 0.f) ? v.w : 0.01f * v.w;
  }
  if (outF) *(float4*)(outF + i) = v;
  if (outB) stbf4(outB + i, v);
}

// Fused BN2(leaky)+LN at the layer boundary
__global__ __launch_bounds__(256) void k_bn_ln(
    const float* __restrict__ Z, const float* __restrict__ scale,
    const float* __restrict__ shift, const float* __restrict__ g,
    const float* __restrict__ b, float* __restrict__ xnOut,
    bf16* __restrict__ actOut) {
  int t = threadIdx.x;
  int row = blockIdx.x * 4 + (t >> 6);
  int c4 = (t & 63) * 4;
  size_t i = (size_t)row * kC + c4;
  float4 z = *(const float4*)(Z + i);
  float4 sc = *(const float4*)(scale + c4);
  float4 sh = *(const float4*)(shift + c4);
  float4 v = make_float4(z.x * sc.x + sh.x, z.y * sc.y + sh.y,
                         z.z * sc.z + sh.z, z.w * sc.w + sh.w);
  v.x = (v.x > 0.f) ? v.x : 0.01f * v.x;
  v.y = (v.y > 0.f) ? v.y : 0.01f * v.y;
  v.z = (v.z > 0.f) ? v.z : 0.01f * v.z;
  v.w = (v.w > 0.f) ? v.w : 0.01f * v.w;
  float s = v.x + v.y + v.z + v.w;
  float q = dot4(v, v);
#pragma unroll
  for (int o = 32; o >= 1; o >>= 1) {
    s += __shfl_xor(s, o);
    q += __shfl_xor(q, o);
  }
  float m = s * (1.f / 256.f);
  float var = q * (1.f / 256.f) - m * m;
  float rs = rsqrtf(var + 1e-6f);
  float4 g4 = *(const float4*)(g + c4);
  float4 b4 = *(const float4*)(b + c4);
  float4 o4 = make_float4((v.x - m) * rs * g4.x + b4.x,
                          (v.y - m) * rs * g4.y + b4.y,
                          (v.z - m) * rs * g4.z + b4.z,
                          (v.w - m) * rs * g4.w + b4.w);
  *(float4*)(xnOut + i) = o4;
  stbf4(actOut + i, o4);
}

// batched f32->bf16 conversion (12 chunks) + bias copies (10 x 256), one
// launch: blockIdx.y < 12 -> cvt; blockIdx.y == 12 -> bias copy.
struct CvtTab {
  const float* src[12];
  bf16* dst[12];
  int n[12];
  const float* bsrc[10];
  float* bdst[10];
};
__global__ __launch_bounds__(256) void k_cvt_multi(CvtTab t) {
  int c = blockIdx.y;
  if (c == 12) {
    if (blockIdx.x < 10) t.bdst[blockIdx.x][threadIdx.x] = t.bsrc[blockIdx.x][threadIdx.x];
    return;
  }
  int i = (blockIdx.x * 256 + threadIdx.x) * 4;
  if (i >= t.n[c]) return;
  float4 v = *(const float4*)(t.src[c] + i);
  stbf4(t.dst[c] + i, v);
}

extern "C" void kernel_launch(void* const* d_in, const int* in_sizes, int n_in,
                              void* d_out, int out_size, void* d_ws, size_t ws_size,
                              hipStream_t stream) {
  const float* data = (const float*)d_in[0];
  const float* ln_g = (const float*)d_in[1];
  const float* ln_b = (const float*)d_in[2];
  const float* jq_w = (const float*)d_in[3];
  const float* jq_b = (const float*)d_in[4];
  const float* jk_w = (const float*)d_in[5];
  const float* jk_b = (const float*)d_in[6];
  const float* jv_w = (const float*)d_in[7];
  const float* jv_b = (const float*)d_in[8];
  const float* jbn_g = (const float*)d_in[9];
  const float* jbn_b = (const float*)d_in[10];
  const float* jf1_w = (const float*)d_in[11];
  const float* jf1_b = (const float*)d_in[12];
  const float* jf2_w = (const float*)d_in[13];
  const float* jf2_b = (const float*)d_in[14];
  const float* jfbn_g = (const float*)d_in[15];
  const float* jfbn_b = (const float*)d_in[16];
  // d_in[17..30]: relay-branch weights — dead code, unused.
  float* out = (float*)d_out;

  // ---- arena ----
  float* f = (float*)d_ws;
  float* nodes = f;    f += SZ_BIG;
  float* xn = f;       f += SZ_BIG;           // LN out -> z -> y2
  float* part = f;     f += 2 * (kRows / 4) * kC;  // BN partials
  float* scale = f;    f += kC;
  float* shift = f;    f += kC;
  float* cb_jqkv = f;  f += 2 * 768;
  float* cb_kv4 = f;   f += 1024;

  bf16* bfa = (bf16*)f;
  bf16* act_bf = bfa;   bfa += SZ_BIG;                 // 17408 x 256
  bf16* embsX_bf = bfa; bfa += (size_t)kRowsE * kC;    // [embs; relay0]
  bf16* P = bfa;        bfa += (size_t)kRows * kDIN;   // qkv (768) / h (1024)
  bf16* akavBuf = bfa;  bfa += (size_t)kRowsE * 1024;  // [k0|v0|k1|v1]
  bf16* Wjqkv = bfa;    bfa += 2 * 768 * 256;
  bf16* Wkv4 = bfa;     bfa += 1024 * 256;
  bf16* Wjf1 = bfa;     bfa += 2 * 1024 * 256;
  bf16* Wjf2 = bfa;     bfa += 2 * 256 * 1024;

  bf16* relay0_bf = embsX_bf + SZ_BIG;  // rows kRows..kRowsE-1
  bf16* qkv_bf = P;                     // 17408 x 768
  bf16* h_bf = P;                       // 17408 x 1024
  float* y2 = xn;

  auto gemm = [&](const bf16* A, const bf16* W, const float* bias,
                  bf16* oB, int M, int N, int flags) {
    dim3 g(M / 128, N / 128);
    k_mfma_gemm<256><<<g, 256, 0, stream>>>(A, W, bias, oB, N, flags);
  };

  // ---- weight conversion + bias copies (one launch) ----
  {
    CvtTab t;
    for (int i = 0; i < 2; ++i) {
      const size_t om = (size_t)i * kC * kC;
      const float* s3[3] = {jq_w + om, jk_w + om, jv_w + om};
      bf16* d3[3] = {Wjqkv + (size_t)i * 768 * 256,
                     Wjqkv + (size_t)i * 768 * 256 + 65536,
                     Wjqkv + (size_t)i * 768 * 256 + 131072};
      for (int j = 0; j < 3; ++j) {
        t.src[i * 3 + j] = s3[j];
        t.dst[i * 3 + j] = d3[j];
        t.n[i * 3 + j] = 65536;
      }
    }
    // Wkv4 = [k0 | v0 | k1 | v1]
    t.src[6] = jk_w;                 t.dst[6] = Wkv4;               t.n[6] = 65536;
    t.src[7] = jv_w;                 t.dst[7] = Wkv4 + 65536;       t.n[7] = 65536;
    t.src[8] = jk_w + (size_t)65536; t.dst[8] = Wkv4 + 131072;      t.n[8] = 65536;
    t.src[9] = jv_w + (size_t)65536; t.dst[9] = Wkv4 + 196608;      t.n[9] = 65536;
    t.src[10] = jf1_w; t.dst[10] = Wjf1; t.n[10] = 2 * 1024 * 256;
    t.src[11] = jf2_w; t.dst[11] = Wjf2; t.n[11] = 2 * 256 * 1024;
    for (int i = 0; i < 2; ++i) {
      t.bsrc[i * 3 + 0] = jq_b + (size_t)i * kC;
      t.bsrc[i * 3 + 1] = jk_b + (size_t)i * kC;
      t.bsrc[i * 3 + 2] = jv_b + (size_t)i * kC;
      t.bdst[i * 3 + 0] = cb_jqkv + i * 768;
      t.bdst[i * 3 + 1] = cb_jqkv + i * 768 + 256;
      t.bdst[i * 3 + 2] = cb_jqkv + i * 768 + 512;
    }
    t.bsrc[6] = jk_b;       t.bdst[6] = cb_kv4;
    t.bsrc[7] = jv_b;       t.bdst[7] = cb_kv4 + 256;
    t.bsrc[8] = jk_b + kC;  t.bdst[8] = cb_kv4 + 512;
    t.bsrc[9] = jv_b + kC;  t.bdst[9] = cb_kv4 + 768;
    k_cvt_multi<<<dim3(512, 13), 256, 0, stream>>>(t);
  }

  k_xform_in<<<dim3(8, 8, 4 * kV), 256, 0, stream>>>(data, nodes, embsX_bf);

  // merged layer-0 LN + relay0 init (both consume nodes)
  k_ln_relay<<<kRows / 4 + kBT / 4, 256, 0, stream>>>(nodes, ln_g, ln_b, xn,
                                                      act_bf, relay0_bf);

  // dual launch: hoisted KV projections (both layers) + layer-0 qkv.
  // GEMM0: [embs;relay0](18432) x Wkv4(1024)  -> akavBuf   (1152 blocks)
  // GEMM1: act_bf(17408)        x Wjqkv0(768) -> qkv_bf    ( 816 blocks)
  {
    const int gx0 = kRowsE / 128, nb0 = gx0 * (1024 / 128);  // 144*8=1152
    const int gx1 = kRows / 128, nb1 = gx1 * (768 / 128);    // 136*6=816
    k_mfma_gemm_dual<<<nb0 + nb1, 256, 0, stream>>>(
        embsX_bf, Wkv4, cb_kv4, akavBuf, 1024, gx0, nb0,
        act_bf, Wjqkv, cb_jqkv, qkv_bf, 768, gx1);
  }

  for (int i = 0; i < 2; ++i) {
    const size_t ob = (size_t)i * kC, ofb1 = (size_t)i * kDIN;
    const bf16* Wf1 = Wjf1 + (size_t)i * 1024 * 256;
    const bf16* Wf2 = Wjf2 + (size_t)i * 256 * 1024;
    const int nbA = kRows / 16;   // attn-fused BN1 partials (16 rows/block)
    const int nbG = kRows / 64;   // f2-64-fused BN2 partials (272)

    if (i == 1) {
      // layer-1 qkv (layer-0 qkv was in the dual launch)
      gemm(act_bf, Wjqkv + (size_t)768 * 256, cb_jqkv + 768, qkv_bf, kRows,
           768, 4);
    }
    // z = xn + att; fused BN1 partial stats (16 rows/block)
    k_attn_sat<<<kRows / 16, 256, 0, stream>>>(qkv_bf,
                                               akavBuf + (size_t)i * 512, xn,
                                               part, nbA);
    k_bn_finalize<<<kC, 256, 0, stream>>>(part, nbA, 1.f / kRows, jbn_g + ob,
                                          jbn_b + ob, scale, shift);
    // BN1 apply -> act_bf only (fp32 residual applied on the fly in f2)
    k_bn_apply<<<kRows / 4, 256, 0, stream>>>(xn, scale, shift, nullptr,
                                              act_bf, 0);
    gemm(act_bf, Wf1, jf1_b + ofb1, h_bf, kRows, 1024, 4 | 1);
    // f2 (64x64 tiles): y2 = h@Wf2 + b + (xn*scale+shift); BN2 partials.
    k_mfma_gemm64<<<dim3(kRows / 64, kC / 64), 256, 0, stream>>>(
        h_bf, Wf2, jf2_b + ob, xn, y2, scale, shift, part, nbG, kC);
    k_bn_finalize<<<kC, 256, 0, stream>>>(part, nbG, 1.f / kRows, jfbn_g + ob,
                                          jfbn_b + ob, scale, shift);
    if (i == 0) {
      // fused BN2(leaky) + layer-1 LN (reads y2, writes xn + act_bf)
      k_bn_ln<<<kRows / 4, 256, 0, stream>>>(y2, scale, shift, ln_g + kC,
                                             ln_b + kC, xn, act_bf);
    }
    // i == 1: BN2 apply + leaky fused into k_xform_out below.
  }

  k_xform_out<<<dim3(8, 8, 4 * kV), 256, 0, stream>>>(y2, scale, shift, out);
  (void)in_sizes; (void)n_in; (void)out_size; (void)ws_size;
}

// Round 16
// 374.633 us; speedup vs baseline: 1.1877x; 1.0006x over previous
//
#include <hip/hip_runtime.h>
#include <hip/hip_bf16.h>

// ---------------------------------------------------------------------------
// Star-Transformer 2-layer forward — satellite branch only (relay chain is
// dead code for the output, established round 10).
// Round 27: r26 base (best: 374.8us) + BN1-apply elimination via weight
// folding: (ret = z*sc+sh) @ W1^T == z @ (sc*W1)^T + (b1 + W1*sh).
//  (1) k_attn_sat also writes xnb = bf16(z) into act_bf (LN-out value is
//      dead there once the qkv GEMM has run; in-order stream).
//  (2) NEW k_fold_w1 (256 blocks, reads 1MB fp32 W1): writes bf16(sc*W1)
//      into the Wjf1 layer slice + exact-fp32 b1eff = b1 + W1*sh.
//  (3) f1 GEMM: act_bf(xnb) x folded-W1 + b1eff.
//  (4) k_bn_apply launch removed (-26.7MB/layer, -1 dispatch/layer).
// Same bf16-quantization count per operand as before; bias-dot exact fp32.
// r26: attn 16 rows/block (4 waves x 4 serial rows, reg sum/sumsq) -21us.
// Locked: 128^2 BK=32-dbuf K=256 GEMMs @4 blocks/CU (lattice closed);
// f2 64x64 BK=64 (r19 -26us); k_ln_relay merge + dual-launch (r23 -8us);
// r13 fusion set; bf16 C-repack through LDS; hoisted K/V projections.
// Row-major activations (row, channel), C=256 contiguous.
// ---------------------------------------------------------------------------

using bf16 = __hip_bfloat16;
typedef __attribute__((ext_vector_type(8))) short bf16x8v;
typedef __attribute__((ext_vector_type(4))) float f32x4;

namespace {
constexpr int kBT = 1024;
constexpr int kC = 256;
constexpr int kV = 17;
constexpr int kT = 256;
constexpr int kDIN = 1024;
constexpr int kRows = kBT * kV;                  // 17408
constexpr int kRowsE = kRows + kBT;              // 18432 = embs + relay0
constexpr float kInvSqrtDk = 0.17677669529663687f;
constexpr size_t SZ_BIG = (size_t)kRows * kC;
}  // namespace

__constant__ int c_nbi[17][5] = {
    {0, 1, 2, 5, 6},   {0, 1, 3, 0, 0},   {0, 2, 4, 0, 0},  {1, 3, 0, 0, 0},
    {2, 4, 0, 0, 0},   {0, 5, 7, 11, 0},  {0, 6, 8, 12, 0}, {5, 7, 9, 0, 0},
    {6, 8, 12, 0, 0},  {7, 9, 0, 0, 0},   {8, 10, 0, 0, 0}, {8, 11, 13, 0, 0},
    {10, 12, 14, 0, 0},{11, 13, 15, 0, 0},{12, 14, 16, 0, 0},
    {13, 15, 0, 0, 0}, {14, 16, 0, 0, 0}};
__constant__ int c_ncnt[17] = {5, 3, 3, 2, 2, 4, 4, 3, 3, 2, 2, 3, 3, 3, 3, 2, 2};

__device__ inline float bf2f(unsigned short s) {
  unsigned int u = ((unsigned int)s) << 16;
  float f;
  __builtin_memcpy(&f, &u, 4);
  return f;
}
__device__ inline unsigned short f2bf(float f) {
  unsigned int u;
  __builtin_memcpy(&u, &f, 4);
  unsigned int r = (u + 0x7fffu + ((u >> 16) & 1u)) >> 16;  // RNE
  return (unsigned short)r;
}
__device__ inline float4 ldbf4(const bf16* p) {
  ushort4 u = *(const ushort4*)p;
  return make_float4(bf2f(u.x), bf2f(u.y), bf2f(u.z), bf2f(u.w));
}
__device__ inline void stbf4(bf16* p, float4 v) {
  ushort4 u = make_ushort4(f2bf(v.x), f2bf(v.y), f2bf(v.z), f2bf(v.w));
  *(ushort4*)p = u;
}
__device__ inline float dot4(float4 a, float4 b) {
  return a.x * b.x + a.y * b.y + a.z * b.z + a.w * b.w;
}

__device__ inline void async16(const bf16* g, bf16* l) {
  __builtin_amdgcn_global_load_lds(
      (const __attribute__((address_space(1))) void*)g,
      (__attribute__((address_space(3))) void*)l, 16, 0, 0);
}

// ---- shared 128x128-tile GEMM body (K=256), bf16-out path ----
// BK=32 double-buffered; 32 KB LDS arena -> 4 blocks/CU.
template <int KT>
__device__ __forceinline__ void gemm128_body(
    char* smem_raw, const bf16* __restrict__ A, const bf16* __restrict__ W,
    const float* __restrict__ bias, bf16* __restrict__ outB, int N, int flags,
    int row0, int col0) {
  bf16* As = (bf16*)smem_raw;              // 2 x 4096 elems (16 KB)
  bf16* Bs = (bf16*)(smem_raw + 16384);    // 2 x 4096 elems (16 KB)
  const int tid = threadIdx.x;
  const int wave = tid >> 6;
  const int lane = tid & 63;

  const int sub = lane >> 2;
  const int kq = (lane & 3) * 8;
  const int rg0 = (2 * wave + 0) * 16;
  const int rg1 = (2 * wave + 1) * 16;
  const bf16* ag0 = A + (size_t)(row0 + rg0 + sub) * KT + kq;
  const bf16* ag1 = A + (size_t)(row0 + rg1 + sub) * KT + kq;
  const bf16* bg0 = W + (size_t)(col0 + rg0 + sub) * KT + kq;
  const bf16* bg1 = W + (size_t)(col0 + rg1 + sub) * KT + kq;

  const int wm = wave >> 1, wn = wave & 1;
  const int fr = lane & 15;
  const int fk = (lane >> 4) * 8;

  f32x4 acc[4][4];
#pragma unroll
  for (int i = 0; i < 4; ++i)
#pragma unroll
    for (int j = 0; j < 4; ++j) acc[i][j] = (f32x4){0.f, 0.f, 0.f, 0.f};

#define STAGE32(buf, koff)                              \
  do {                                                  \
    async16(ag0 + (koff), As + (buf) * 4096 + rg0 * 32); \
    async16(ag1 + (koff), As + (buf) * 4096 + rg1 * 32); \
    async16(bg0 + (koff), Bs + (buf) * 4096 + rg0 * 32); \
    async16(bg1 + (koff), Bs + (buf) * 4096 + rg1 * 32); \
  } while (0)

  STAGE32(0, 0);
  __syncthreads();  // buf0 ready

  for (int k0 = 0; k0 < KT; k0 += 32) {
    const int cur = (k0 >> 5) & 1;
    if (k0 + 32 < KT) STAGE32(cur ^ 1, k0 + 32);  // in flight during MFMA
    bf16x8v af[4], bfv[4];
#pragma unroll
    for (int i = 0; i < 4; ++i)
      af[i] = *(const bf16x8v*)&As[cur * 4096 +
                                   (wm * 64 + i * 16 + fr) * 32 + fk];
#pragma unroll
    for (int j = 0; j < 4; ++j)
      bfv[j] = *(const bf16x8v*)&Bs[cur * 4096 +
                                    (wn * 64 + j * 16 + fr) * 32 + fk];
#pragma unroll
    for (int i = 0; i < 4; ++i)
#pragma unroll
      for (int j = 0; j < 4; ++j)
        acc[i][j] = __builtin_amdgcn_mfma_f32_16x16x32_bf16(af[i], bfv[j],
                                                            acc[i][j], 0, 0,
                                                            0);
    __syncthreads();
  }
#undef STAGE32

  // bf16 out: stage C-tile in LDS (ushort 128x128 = 32 KB arena), then
  // 8 passes of 16 rows x 256B fully-coalesced stores.
  unsigned short* cs = (unsigned short*)smem_raw;
#pragma unroll
  for (int j = 0; j < 4; ++j) {
    int lc = wn * 64 + j * 16 + fr;
    float bv = bias ? bias[col0 + lc] : 0.f;
#pragma unroll
    for (int i = 0; i < 4; ++i) {
      int lr = wm * 64 + i * 16 + (lane >> 4) * 4;
#pragma unroll
      for (int r = 0; r < 4; ++r) {
        float v = acc[i][j][r] + bv;
        if (flags & 1) v = fmaxf(v, 0.f);
        cs[(lr + r) * 128 + lc] = f2bf(v);
      }
    }
  }
  __syncthreads();
#pragma unroll
  for (int p = 0; p < 8; ++p) {
    int lr = p * 16 + (tid >> 4);
    int lc = (tid & 15) * 8;
    *(bf16x8v*)&outB[(size_t)(row0 + lr) * N + col0 + lc] =
        *(const bf16x8v*)&cs[lr * 128 + lc];
  }
}

// ---- single GEMM launch (K=256) ----
template <int KT>
__global__ __launch_bounds__(256, 4) void k_mfma_gemm(
    const bf16* __restrict__ A, const bf16* __restrict__ W,
    const float* __restrict__ bias, bf16* __restrict__ outB, int N,
    int flags) {
  __shared__ __align__(16) char smem_raw[32768];
  gemm128_body<KT>(smem_raw, A, W, bias, outB, N, flags, blockIdx.x * 128,
                   blockIdx.y * 128);
}

// ---- dual GEMM launch: two independent K=256 bf16-out GEMMs in one grid.
// Blocks [0, nb0) run GEMM0 (gx0 row-tiles fastest); rest run GEMM1.
__global__ __launch_bounds__(256, 4) void k_mfma_gemm_dual(
    const bf16* __restrict__ A0, const bf16* __restrict__ W0,
    const float* __restrict__ b0, bf16* __restrict__ o0, int N0, int gx0,
    int nb0, const bf16* __restrict__ A1, const bf16* __restrict__ W1,
    const float* __restrict__ b1, bf16* __restrict__ o1, int N1, int gx1) {
  __shared__ __align__(16) char smem_raw[32768];
  const int bid = blockIdx.x;
  if (bid < nb0) {
    int bx = bid % gx0, by = bid / gx0;
    gemm128_body<256>(smem_raw, A0, W0, b0, o0, N0, 4, bx * 128, by * 128);
  } else {
    int local = bid - nb0;
    int bx = local % gx1, by = local / gx1;
    gemm128_body<256>(smem_raw, A1, W1, b1, o1, N1, 4, bx * 128, by * 128);
  }
}

// ---- f2-dedicated 64x64-tile GEMM: KT=1024, fp32 out, BN1-residual apply
// + BN2 partial stats. Grid (M/64, N/64) = 1088 blocks -> ~4 blocks/CU.
__global__ __launch_bounds__(256, 4) void k_mfma_gemm64(
    const bf16* __restrict__ A, const bf16* __restrict__ W,
    const float* __restrict__ bias, const float* __restrict__ res,
    float* __restrict__ outF, const float* __restrict__ bnScI,
    const float* __restrict__ bnShI, float* __restrict__ partOut, int nbPart,
    int N) {
  constexpr int KT = 1024;
  __shared__ __align__(16) bf16 As[2][4096];  // 2 x (2 chunks x 64 x 32)
  __shared__ __align__(16) bf16 Bs[2][4096];
  __shared__ float sred[4 * 64];
  __shared__ float qred[4 * 64];
  const int tid = threadIdx.x;
  const int wave = tid >> 6;
  const int lane = tid & 63;
  const int row0 = blockIdx.x * 64;
  const int col0 = blockIdx.y * 64;

  // global src per-lane: row wave*16 + (lane>>2), cols (lane&3)*8..+7
  const int srow = wave * 16 + (lane >> 2);
  const int skq = (lane & 3) * 8;
  const bf16* ag = A + (size_t)(row0 + srow) * KT + skq;
  const bf16* bg = W + (size_t)(col0 + srow) * KT + skq;

  const int wm = wave >> 1, wn = wave & 1;
  const int fr = lane & 15;
  const int fk = (lane >> 4) * 8;

  f32x4 acc[2][2];
#pragma unroll
  for (int i = 0; i < 2; ++i)
#pragma unroll
    for (int j = 0; j < 2; ++j) acc[i][j] = (f32x4){0.f, 0.f, 0.f, 0.f};

  // LDS dest: wave-uniform base; HW scatters lane i at +16B*i.
#define STAGE64x64(buf, koff)                                      \
  do {                                                             \
    _Pragma("unroll") for (int kc = 0; kc < 2; ++kc) {             \
      async16(ag + (koff) + kc * 32,                               \
              &As[(buf)][kc * 2048 + wave * 512]);                 \
      async16(bg + (koff) + kc * 32,                               \
              &Bs[(buf)][kc * 2048 + wave * 512]);                 \
    }                                                              \
  } while (0)

  STAGE64x64(0, 0);
  __syncthreads();

  for (int k0 = 0; k0 < KT; k0 += 64) {
    const int cur = (k0 >> 6) & 1;
    if (k0 + 64 < KT) STAGE64x64(cur ^ 1, k0 + 64);
#pragma unroll
    for (int kc = 0; kc < 2; ++kc) {
      bf16x8v af[2], bfv[2];
#pragma unroll
      for (int i = 0; i < 2; ++i)
        af[i] = *(const bf16x8v*)&As[cur][kc * 2048 +
                                          (wm * 32 + i * 16 + fr) * 32 + fk];
#pragma unroll
      for (int j = 0; j < 2; ++j)
        bfv[j] = *(const bf16x8v*)&Bs[cur][kc * 2048 +
                                           (wn * 32 + j * 16 + fr) * 32 + fk];
#pragma unroll
      for (int i = 0; i < 2; ++i)
#pragma unroll
        for (int j = 0; j < 2; ++j)
          acc[i][j] = __builtin_amdgcn_mfma_f32_16x16x32_bf16(af[i], bfv[j],
                                                              acc[i][j], 0, 0,
                                                              0);
    }
    __syncthreads();
  }
#undef STAGE64x64

  // fp32 epilogue: out = acc + bias + res*bnSc + bnSh; BN2 partial stats.
  const int crow = row0 + wm * 32;
  const int ccol = col0 + wn * 32;
  float colS[2] = {0.f, 0.f};
  float colQ[2] = {0.f, 0.f};
#pragma unroll
  for (int j = 0; j < 2; ++j) {
    int col = ccol + j * 16 + fr;
    float bv = bias[col];
    float rsc = bnScI[col], rsh = bnShI[col];
#pragma unroll
    for (int i = 0; i < 2; ++i) {
      int rowb = crow + i * 16 + (lane >> 4) * 4;
#pragma unroll
      for (int r = 0; r < 4; ++r) {
        size_t row = (size_t)(rowb + r);
        float v = acc[i][j][r] + bv + res[row * N + col] * rsc + rsh;
        outF[row * N + col] = v;
        colS[j] += v;
        colQ[j] += v * v;
      }
    }
  }
  // reduce the 4 row-groups within the wave (lane bit4, bit5)
#pragma unroll
  for (int j = 0; j < 2; ++j) {
    colS[j] += __shfl_xor(colS[j], 16);
    colS[j] += __shfl_xor(colS[j], 32);
    colQ[j] += __shfl_xor(colQ[j], 16);
    colQ[j] += __shfl_xor(colQ[j], 32);
  }
  if (lane < 16) {
#pragma unroll
    for (int j = 0; j < 2; ++j) {
      sred[wave * 64 + j * 16 + fr] = colS[j];
      qred[wave * 64 + j * 16 + fr] = colQ[j];
    }
  }
  __syncthreads();
  if (tid < 64) {
    int c = tid;
    int wsel = c >> 5, off = c & 31;
    float s = sred[wsel * 64 + off] + sred[(wsel + 2) * 64 + off];
    float q = qred[wsel * 64 + off] + qred[(wsel + 2) * 64 + off];
    int col = col0 + c;
    partOut[(size_t)blockIdx.x * kC + col] = s;
    partOut[(size_t)(nbPart + blockIdx.x) * kC + col] = q;
  }
}

// ---- BN1 fold into f1 weights: W1f[h][c] = bf16(W1[h][c]*scale[c]);
// b1eff[h] = b1[h] + sum_c W1[h][c]*shift[c] (exact fp32 dot).
// Grid 256 blocks x 256 threads; 4 rows h per block.
__global__ __launch_bounds__(256) void k_fold_w1(
    const float* __restrict__ w1, const float* __restrict__ b1,
    const float* __restrict__ scale, const float* __restrict__ shift,
    bf16* __restrict__ w1f, float* __restrict__ b1eff) {
  __shared__ float red[4][4];
  int c = threadIdx.x;
  int wave = c >> 6, lane = c & 63;
  float sc = scale[c], sh = shift[c];
#pragma unroll
  for (int r = 0; r < 4; ++r) {
    int h = blockIdx.x * 4 + r;
    float w = w1[(size_t)h * kC + c];
    w1f[(size_t)h * kC + c] = __float2bfloat16(w * sc);
    float d = w * sh;
#pragma unroll
    for (int o = 32; o >= 1; o >>= 1) d += __shfl_xor(d, o);
    if (lane == 0) red[r][wave] = d;
  }
  __syncthreads();
  if (c < 4) {
    int h = blockIdx.x * 4 + c;
    b1eff[h] = b1[h] + red[c][0] + red[c][1] + red[c][2] + red[c][3];
  }
}

// data (B,C,V,T) -> nodes fp32 rows + embs bf16 rows
__global__ __launch_bounds__(256) void k_xform_in(const float* __restrict__ data,
                                                  float* __restrict__ nodes,
                                                  bf16* __restrict__ embs_bf) {
  __shared__ float tile[32][33];
  int ct = blockIdx.x * 32, tt = blockIdx.y * 32;
  int bv = blockIdx.z;
  int b = bv / kV, v = bv - b * kV;
  int tx = threadIdx.x & 31, ty = threadIdx.x >> 5;
  for (int i = ty; i < 32; i += 8)
    tile[i][tx] = data[(((size_t)b * kC + ct + i) * kV + v) * kT + tt + tx];
  __syncthreads();
  for (int i = ty; i < 32; i += 8) {
    size_t s = (size_t)b * kT + tt + i;
    size_t idx = (s * kV + v) * kC + ct + tx;
    float val = tile[tx][i];
    nodes[idx] = val;
    embs_bf[idx] = __float2bfloat16(val);
  }
}

// final transpose fused with BN2-apply + leaky
__global__ __launch_bounds__(256) void k_xform_out(const float* __restrict__ Z,
                                                   const float* __restrict__ scale,
                                                   const float* __restrict__ shift,
                                                   float* __restrict__ out) {
  __shared__ float tile[32][33];
  int ct = blockIdx.x * 32, tt = blockIdx.y * 32;
  int bv = blockIdx.z;
  int b = bv / kV, v = bv - b * kV;
  int tx = threadIdx.x & 31, ty = threadIdx.x >> 5;
  float sc = scale[ct + tx], sh = shift[ct + tx];
  for (int i = ty; i < 32; i += 8) {
    size_t s = (size_t)b * kT + tt + i;
    float val = Z[(s * kV + v) * kC + ct + tx] * sc + sh;
    val = (val > 0.f) ? val : 0.01f * val;
    tile[i][tx] = val;
  }
  __syncthreads();
  for (int i = ty; i < 32; i += 8)
    out[(((size_t)b * kC + ct + i) * kV + v) * kT + tt + tx] = tile[tx][i];
}

// merged: layer-0 LN (blocks [0, kRows/4)) + relay0 init (rest).
// Both are independent consumers of nodes.
__global__ __launch_bounds__(256) void k_ln_relay(
    const float* __restrict__ nodes, const float* __restrict__ g,
    const float* __restrict__ b, float* __restrict__ O,
    bf16* __restrict__ Ob, bf16* __restrict__ relay0_bf) {
  int t = threadIdx.x;
  int bid = blockIdx.x;
  if (bid < kRows / 4) {
    int row = bid * 4 + (t >> 6);
    int c4 = (t & 63) * 4;
    size_t i = (size_t)row * kC + c4;
    float4 x = *(const float4*)(nodes + i);
    float s = x.x + x.y + x.z + x.w;
    float q = dot4(x, x);
#pragma unroll
    for (int o = 32; o >= 1; o >>= 1) {
      s += __shfl_xor(s, o);
      q += __shfl_xor(q, o);
    }
    float m = s * (1.f / 256.f);
    float var = q * (1.f / 256.f) - m * m;
    float rs = rsqrtf(var + 1e-6f);
    float4 g4 = *(const float4*)(g + c4);
    float4 b4 = *(const float4*)(b + c4);
    float4 o4 = make_float4((x.x - m) * rs * g4.x + b4.x,
                            (x.y - m) * rs * g4.y + b4.y,
                            (x.z - m) * rs * g4.z + b4.z,
                            (x.w - m) * rs * g4.w + b4.w);
    *(float4*)(O + i) = o4;
    stbf4(Ob + i, o4);
  } else {
    int s = (bid - kRows / 4) * 4 + (t >> 6);
    int c4 = (t & 63) * 4;
    float4 acc = make_float4(0.f, 0.f, 0.f, 0.f);
#pragma unroll
    for (int v = 0; v < kV; ++v) {
      float4 x = *(const float4*)(nodes + ((size_t)s * kV + v) * kC + c4);
      acc.x += x.x; acc.y += x.y; acc.z += x.z; acc.w += x.w;
    }
    float4 r =
        make_float4(acc.x / 17.f, acc.y / 17.f, acc.z / 17.f, acc.w / 17.f);
    stbf4(relay0_bf + (size_t)s * kC + c4, r);
  }
}

// satellite attention + fused BN1 partial stats. 16 rows/block: 4 waves x
// 4 rows each (serial per wave, register-accumulated sum/sumsq), then the
// cross-wave LDS combine -> part rows = kRows/16 = 1088. Also writes
// xnb = bf16(z) for the weight-folded f1 GEMM.
__global__ __launch_bounds__(256) void k_attn_sat(const bf16* __restrict__ qkv,
                                                  const bf16* __restrict__ akav,
                                                  float* __restrict__ z,
                                                  bf16* __restrict__ xnb,
                                                  float* __restrict__ part,
                                                  int nb) {
  __shared__ float sS[4][256];
  __shared__ float qS[4][256];
  int t = threadIdx.x;
  int w = t >> 6;
  int lane = t & 63;
  int c4 = lane * 4;
  float sAcc[4] = {0.f, 0.f, 0.f, 0.f};
  float qAcc[4] = {0.f, 0.f, 0.f, 0.f};
  for (int r = 0; r < 4; ++r) {
    int rl = blockIdx.x * 16 + w * 4 + r;
    int s = rl / kV, l = rl - s * kV;
    float4 q = ldbf4(qkv + (size_t)rl * 768 + c4);
    int cnt = c_ncnt[l];
    float sc[7];
    int nrow[5];
#pragma unroll
    for (int wd = 0; wd < 5; ++wd) {
      nrow[wd] = s * kV + c_nbi[l][wd];
      float4 k = ldbf4(qkv + (size_t)nrow[wd] * 768 + 256 + c4);
      float p = dot4(q, k);
      p += __shfl_xor(p, 1, 8);
      p += __shfl_xor(p, 2, 8);
      p += __shfl_xor(p, 4, 8);
      sc[wd] = (wd < cnt) ? p * kInvSqrtDk : -1e30f;
    }
    {
      float4 k = ldbf4(akav + (size_t)rl * 1024 + c4);
      float p = dot4(q, k);
      p += __shfl_xor(p, 1, 8);
      p += __shfl_xor(p, 2, 8);
      p += __shfl_xor(p, 4, 8);
      sc[5] = p * kInvSqrtDk;
    }
    {
      float4 k = ldbf4(akav + (size_t)(kRows + s) * 1024 + c4);
      float p = dot4(q, k);
      p += __shfl_xor(p, 1, 8);
      p += __shfl_xor(p, 2, 8);
      p += __shfl_xor(p, 4, 8);
      sc[6] = p * kInvSqrtDk;
    }
    float mx = sc[0];
#pragma unroll
    for (int wd = 1; wd < 7; ++wd) mx = fmaxf(mx, sc[wd]);
    float den = 0.f;
#pragma unroll
    for (int wd = 0; wd < 7; ++wd) {
      sc[wd] = __expf(sc[wd] - mx);
      den += sc[wd];
    }
    float inv = 1.f / den;
    float4 acc = make_float4(0.f, 0.f, 0.f, 0.f);
#pragma unroll
    for (int wd = 0; wd < 5; ++wd) {
      float4 v = ldbf4(qkv + (size_t)nrow[wd] * 768 + 512 + c4);
      acc.x += sc[wd] * v.x; acc.y += sc[wd] * v.y;
      acc.z += sc[wd] * v.z; acc.w += sc[wd] * v.w;
    }
    {
      float4 v = ldbf4(akav + (size_t)rl * 1024 + 256 + c4);
      acc.x += sc[5] * v.x; acc.y += sc[5] * v.y;
      acc.z += sc[5] * v.z; acc.w += sc[5] * v.w;
    }
    {
      float4 v = ldbf4(akav + (size_t)(kRows + s) * 1024 + 256 + c4);
      acc.x += sc[6] * v.x; acc.y += sc[6] * v.y;
      acc.z += sc[6] * v.z; acc.w += sc[6] * v.w;
    }
    size_t zi = (size_t)rl * kC + c4;
    float4 xv = *(const float4*)(z + zi);
    float4 o = make_float4(xv.x + acc.x * inv, xv.y + acc.y * inv,
                           xv.z + acc.z * inv, xv.w + acc.w * inv);
    *(float4*)(z + zi) = o;
    stbf4(xnb + zi, o);  // bf16 copy for weight-folded f1
    sAcc[0] += o.x; sAcc[1] += o.y; sAcc[2] += o.z; sAcc[3] += o.w;
    qAcc[0] += o.x * o.x; qAcc[1] += o.y * o.y;
    qAcc[2] += o.z * o.z; qAcc[3] += o.w * o.w;
  }
  sS[w][c4 + 0] = sAcc[0]; sS[w][c4 + 1] = sAcc[1];
  sS[w][c4 + 2] = sAcc[2]; sS[w][c4 + 3] = sAcc[3];
  qS[w][c4 + 0] = qAcc[0]; qS[w][c4 + 1] = qAcc[1];
  qS[w][c4 + 2] = qAcc[2]; qS[w][c4 + 3] = qAcc[3];
  __syncthreads();
  float ps = sS[0][t] + sS[1][t] + sS[2][t] + sS[3][t];
  float pq = qS[0][t] + qS[1][t] + qS[2][t] + qS[3][t];
  part[(size_t)blockIdx.x * kC + t] = ps;
  part[(size_t)(nb + blockIdx.x) * kC + t] = pq;
}

// BN stage 2: block per channel
__global__ __launch_bounds__(256) void k_bn_finalize(const float* __restrict__ part,
                                                     int nb, float inv_n,
                                                     const float* __restrict__ g,
                                                     const float* __restrict__ b,
                                                     float* __restrict__ scale,
                                                     float* __restrict__ shift) {
  int c = blockIdx.x;
  int t = threadIdx.x;
  float s = 0.f, q = 0.f;
  for (int i = t; i < nb; i += 256) {
    s += part[(size_t)i * kC + c];
    q += part[(size_t)(nb + i) * kC + c];
  }
#pragma unroll
  for (int o = 32; o >= 1; o >>= 1) {
    s += __shfl_xor(s, o);
    q += __shfl_xor(q, o);
  }
  __shared__ float ws[4], wq[4];
  int wid = t >> 6;
  if ((t & 63) == 0) { ws[wid] = s; wq[wid] = q; }
  __syncthreads();
  if (t == 0) {
    float S = ws[0] + ws[1] + ws[2] + ws[3];
    float Q = wq[0] + wq[1] + wq[2] + wq[3];
    float m = S * inv_n;
    float var = Q * inv_n - m * m;
    float sc = g[c] * rsqrtf(var + 1e-5f);
    scale[c] = sc;
    shift[c] = b[c] - m * sc;
  }
}

// Fused BN2(leaky)+LN at the layer boundary
__global__ __launch_bounds__(256) void k_bn_ln(
    const float* __restrict__ Z, const float* __restrict__ scale,
    const float* __restrict__ shift, const float* __restrict__ g,
    const float* __restrict__ b, float* __restrict__ xnOut,
    bf16* __restrict__ actOut) {
  int t = threadIdx.x;
  int row = blockIdx.x * 4 + (t >> 6);
  int c4 = (t & 63) * 4;
  size_t i = (size_t)row * kC + c4;
  float4 z = *(const float4*)(Z + i);
  float4 sc = *(const float4*)(scale + c4);
  float4 sh = *(const float4*)(shift + c4);
  float4 v = make_float4(z.x * sc.x + sh.x, z.y * sc.y + sh.y,
                         z.z * sc.z + sh.z, z.w * sc.w + sh.w);
  v.x = (v.x > 0.f) ? v.x : 0.01f * v.x;
  v.y = (v.y > 0.f) ? v.y : 0.01f * v.y;
  v.z = (v.z > 0.f) ? v.z : 0.01f * v.z;
  v.w = (v.w > 0.f) ? v.w : 0.01f * v.w;
  float s = v.x + v.y + v.z + v.w;
  float q = dot4(v, v);
#pragma unroll
  for (int o = 32; o >= 1; o >>= 1) {
    s += __shfl_xor(s, o);
    q += __shfl_xor(q, o);
  }
  float m = s * (1.f / 256.f);
  float var = q * (1.f / 256.f) - m * m;
  float rs = rsqrtf(var + 1e-6f);
  float4 g4 = *(const float4*)(g + c4);
  float4 b4 = *(const float4*)(b + c4);
  float4 o4 = make_float4((v.x - m) * rs * g4.x + b4.x,
                          (v.y - m) * rs * g4.y + b4.y,
                          (v.z - m) * rs * g4.z + b4.z,
                          (v.w - m) * rs * g4.w + b4.w);
  *(float4*)(xnOut + i) = o4;
  stbf4(actOut + i, o4);
}

// batched f32->bf16 conversion (12 chunks) + bias copies (10 x 256), one
// launch: blockIdx.y < 12 -> cvt; blockIdx.y == 12 -> bias copy.
// chunk 10 disabled (n=0): Wjf1 now produced per-layer by k_fold_w1.
struct CvtTab {
  const float* src[12];
  bf16* dst[12];
  int n[12];
  const float* bsrc[10];
  float* bdst[10];
};
__global__ __launch_bounds__(256) void k_cvt_multi(CvtTab t) {
  int c = blockIdx.y;
  if (c == 12) {
    if (blockIdx.x < 10) t.bdst[blockIdx.x][threadIdx.x] = t.bsrc[blockIdx.x][threadIdx.x];
    return;
  }
  int i = (blockIdx.x * 256 + threadIdx.x) * 4;
  if (i >= t.n[c]) return;
  float4 v = *(const float4*)(t.src[c] + i);
  stbf4(t.dst[c] + i, v);
}

extern "C" void kernel_launch(void* const* d_in, const int* in_sizes, int n_in,
                              void* d_out, int out_size, void* d_ws, size_t ws_size,
                              hipStream_t stream) {
  const float* data = (const float*)d_in[0];
  const float* ln_g = (const float*)d_in[1];
  const float* ln_b = (const float*)d_in[2];
  const float* jq_w = (const float*)d_in[3];
  const float* jq_b = (const float*)d_in[4];
  const float* jk_w = (const float*)d_in[5];
  const float* jk_b = (const float*)d_in[6];
  const float* jv_w = (const float*)d_in[7];
  const float* jv_b = (const float*)d_in[8];
  const float* jbn_g = (const float*)d_in[9];
  const float* jbn_b = (const float*)d_in[10];
  const float* jf1_w = (const float*)d_in[11];
  const float* jf1_b = (const float*)d_in[12];
  const float* jf2_w = (const float*)d_in[13];
  const float* jf2_b = (const float*)d_in[14];
  const float* jfbn_g = (const float*)d_in[15];
  const float* jfbn_b = (const float*)d_in[16];
  // d_in[17..30]: relay-branch weights — dead code, unused.
  float* out = (float*)d_out;

  // ---- arena ----
  float* f = (float*)d_ws;
  float* nodes = f;    f += SZ_BIG;
  float* xn = f;       f += SZ_BIG;           // LN out -> z -> y2
  float* part = f;     f += 2 * (kRows / 4) * kC;  // BN partials
  float* scale = f;    f += kC;
  float* shift = f;    f += kC;
  float* b1eff = f;    f += kDIN;             // folded f1 bias (per layer)
  float* cb_jqkv = f;  f += 2 * 768;
  float* cb_kv4 = f;   f += 1024;

  bf16* bfa = (bf16*)f;
  bf16* act_bf = bfa;   bfa += SZ_BIG;                 // 17408 x 256
  bf16* embsX_bf = bfa; bfa += (size_t)kRowsE * kC;    // [embs; relay0]
  bf16* P = bfa;        bfa += (size_t)kRows * kDIN;   // qkv (768) / h (1024)
  bf16* akavBuf = bfa;  bfa += (size_t)kRowsE * 1024;  // [k0|v0|k1|v1]
  bf16* Wjqkv = bfa;    bfa += 2 * 768 * 256;
  bf16* Wkv4 = bfa;     bfa += 1024 * 256;
  bf16* Wjf1 = bfa;     bfa += 2 * 1024 * 256;         // folded per layer
  bf16* Wjf2 = bfa;     bfa += 2 * 256 * 1024;

  bf16* relay0_bf = embsX_bf + SZ_BIG;  // rows kRows..kRowsE-1
  bf16* qkv_bf = P;                     // 17408 x 768
  bf16* h_bf = P;                       // 17408 x 1024
  float* y2 = xn;

  auto gemm = [&](const bf16* A, const bf16* W, const float* bias,
                  bf16* oB, int M, int N, int flags) {
    dim3 g(M / 128, N / 128);
    k_mfma_gemm<256><<<g, 256, 0, stream>>>(A, W, bias, oB, N, flags);
  };

  // ---- weight conversion + bias copies (one launch) ----
  {
    CvtTab t;
    for (int i = 0; i < 2; ++i) {
      const size_t om = (size_t)i * kC * kC;
      const float* s3[3] = {jq_w + om, jk_w + om, jv_w + om};
      bf16* d3[3] = {Wjqkv + (size_t)i * 768 * 256,
                     Wjqkv + (size_t)i * 768 * 256 + 65536,
                     Wjqkv + (size_t)i * 768 * 256 + 131072};
      for (int j = 0; j < 3; ++j) {
        t.src[i * 3 + j] = s3[j];
        t.dst[i * 3 + j] = d3[j];
        t.n[i * 3 + j] = 65536;
      }
    }
    // Wkv4 = [k0 | v0 | k1 | v1]
    t.src[6] = jk_w;                 t.dst[6] = Wkv4;               t.n[6] = 65536;
    t.src[7] = jv_w;                 t.dst[7] = Wkv4 + 65536;       t.n[7] = 65536;
    t.src[8] = jk_w + (size_t)65536; t.dst[8] = Wkv4 + 131072;      t.n[8] = 65536;
    t.src[9] = jv_w + (size_t)65536; t.dst[9] = Wkv4 + 196608;      t.n[9] = 65536;
    t.src[10] = jf2_w; t.dst[10] = Wjf2; t.n[10] = 0;   // disabled (fold)
    t.src[11] = jf2_w; t.dst[11] = Wjf2; t.n[11] = 2 * 256 * 1024;
    for (int i = 0; i < 2; ++i) {
      t.bsrc[i * 3 + 0] = jq_b + (size_t)i * kC;
      t.bsrc[i * 3 + 1] = jk_b + (size_t)i * kC;
      t.bsrc[i * 3 + 2] = jv_b + (size_t)i * kC;
      t.bdst[i * 3 + 0] = cb_jqkv + i * 768;
      t.bdst[i * 3 + 1] = cb_jqkv + i * 768 + 256;
      t.bdst[i * 3 + 2] = cb_jqkv + i * 768 + 512;
    }
    t.bsrc[6] = jk_b;       t.bdst[6] = cb_kv4;
    t.bsrc[7] = jv_b;       t.bdst[7] = cb_kv4 + 256;
    t.bsrc[8] = jk_b + kC;  t.bdst[8] = cb_kv4 + 512;
    t.bsrc[9] = jv_b + kC;  t.bdst[9] = cb_kv4 + 768;
    k_cvt_multi<<<dim3(512, 13), 256, 0, stream>>>(t);
  }

  k_xform_in<<<dim3(8, 8, 4 * kV), 256, 0, stream>>>(data, nodes, embsX_bf);

  // merged layer-0 LN + relay0 init (both consume nodes)
  k_ln_relay<<<kRows / 4 + kBT / 4, 256, 0, stream>>>(nodes, ln_g, ln_b, xn,
                                                      act_bf, relay0_bf);

  // dual launch: hoisted KV projections (both layers) + layer-0 qkv.
  {
    const int gx0 = kRowsE / 128, nb0 = gx0 * (1024 / 128);  // 144*8=1152
    const int gx1 = kRows / 128, nb1 = gx1 * (768 / 128);    // 136*6=816
    k_mfma_gemm_dual<<<nb0 + nb1, 256, 0, stream>>>(
        embsX_bf, Wkv4, cb_kv4, akavBuf, 1024, gx0, nb0,
        act_bf, Wjqkv, cb_jqkv, qkv_bf, 768, gx1);
  }

  for (int i = 0; i < 2; ++i) {
    const size_t ob = (size_t)i * kC;
    bf16* Wf1 = Wjf1 + (size_t)i * 1024 * 256;
    const bf16* Wf2 = Wjf2 + (size_t)i * 256 * 1024;
    const int nbA = kRows / 16;   // attn-fused BN1 partials (16 rows/block)
    const int nbG = kRows / 64;   // f2-64-fused BN2 partials (272)

    if (i == 1) {
      // layer-1 qkv (layer-0 qkv was in the dual launch)
      gemm(act_bf, Wjqkv + (size_t)768 * 256, cb_jqkv + 768, qkv_bf, kRows,
           768, 4);
    }
    // z = xn + att; fused BN1 partial stats; writes xnb=bf16(z) into act_bf
    // (its LN-out content is dead once the qkv GEMM above consumed it).
    k_attn_sat<<<kRows / 16, 256, 0, stream>>>(qkv_bf,
                                               akavBuf + (size_t)i * 512, xn,
                                               act_bf, part, nbA);
    k_bn_finalize<<<kC, 256, 0, stream>>>(part, nbA, 1.f / kRows, jbn_g + ob,
                                          jbn_b + ob, scale, shift);
    // fold BN1 affine into f1 weights (replaces the k_bn_apply pass)
    k_fold_w1<<<kDIN / 4, 256, 0, stream>>>(jf1_w + (size_t)i * kDIN * kC,
                                            jf1_b + (size_t)i * kDIN, scale,
                                            shift, Wf1, b1eff);
    gemm(act_bf, Wf1, b1eff, h_bf, kRows, 1024, 4 | 1);
    // f2 (64x64 tiles): y2 = h@Wf2 + b + (xn*scale+shift); BN2 partials.
    k_mfma_gemm64<<<dim3(kRows / 64, kC / 64), 256, 0, stream>>>(
        h_bf, Wf2, jf2_b + ob, xn, y2, scale, shift, part, nbG, kC);
    k_bn_finalize<<<kC, 256, 0, stream>>>(part, nbG, 1.f / kRows, jfbn_g + ob,
                                          jfbn_b + ob, scale, shift);
    if (i == 0) {
      // fused BN2(leaky) + layer-1 LN (reads y2, writes xn + act_bf)
      k_bn_ln<<<kRows / 4, 256, 0, stream>>>(y2, scale, shift, ln_g + kC,
                                             ln_b + kC, xn, act_bf);
    }
    // i == 1: BN2 apply + leaky fused into k_xform_out below.
  }

  k_xform_out<<<dim3(8, 8, 4 * kV), 256, 0, stream>>>(y2, scale, shift, out);
  (void)in_sizes; (void)n_in; (void)out_size; (void)ws_size;
}